// Round 1
// baseline (1987.050 us; speedup 1.0000x reference)
//
#include <hip/hip_runtime.h>
#include <math.h>

#define NBATCH 512
#define NL 16
#define DD 128
#define HH 4
#define HD 32

// ---------------- segment table (batch arrays are sorted) ----------------
__global__ void seg_kernel(const int* __restrict__ db, int nd,
                           const int* __restrict__ eb, int ne,
                           int* __restrict__ seg) {
  const int* arr = (blockIdx.x == 0) ? db : eb;
  int n = (blockIdx.x == 0) ? nd : ne;
  int* start = seg + blockIdx.x * 1024;
  int* cnt = start + 512;
  int b = threadIdx.x;
  if (b < 512) {
    int lo = 0, hi = n;
    while (lo < hi) { int mid = (lo + hi) >> 1; if (arr[mid] < b) lo = mid + 1; else hi = mid; }
    int s = lo;
    lo = s; hi = n;
    while (lo < hi) { int mid = (lo + hi) >> 1; if (arr[mid] < b + 1) lo = mid + 1; else hi = mid; }
    start[b] = s; cnt[b] = lo - s;
  }
}

// ---------------- lat init: broadcast latents ----------------
__global__ void init_lat_kernel(const float* __restrict__ latents, float* __restrict__ lat) {
  int i = blockIdx.x * blockDim.x + threadIdx.x;  // 512*2048 total
  lat[i] = latents[i & 2047];
}

// ---------------- fold q-projection chain: Wq_f = wq_mha @ wq, scaled by 1/sqrt(32) ----------------
__global__ void fold_kernel(const float* __restrict__ wq_d, const float* __restrict__ bq_d,
                            const float* __restrict__ wq_e, const float* __restrict__ bq_e,
                            const float* __restrict__ mw_d, const float* __restrict__ mb_d,
                            const float* __restrict__ mw_e, const float* __restrict__ mb_e,
                            float* __restrict__ Wqf, float* __restrict__ bqf) {
  int l = blockIdx.x >> 1, p = blockIdx.x & 1;
  const float* wq = (p == 0 ? wq_d : wq_e) + l * 16384;
  const float* bq = (p == 0 ? bq_d : bq_e) + l * 128;
  const float* mw = (p == 0 ? mw_d : mw_e) + l * 49152;   // rows 0..127 = q-proj of fused mha weight
  const float* mb = (p == 0 ? mb_d : mb_e) + l * 384;
  float* W = Wqf + (size_t)blockIdx.x * 16384;
  float* bb = bqf + blockIdx.x * 128;
  const float scale = 0.17677669529663687f;  // 1/sqrt(32)
  for (int e = threadIdx.x; e < 16384; e += blockDim.x) {
    int i = e >> 7, j = e & 127;
    float s = 0.f;
    const float* mr = mw + i * 128;
    for (int k = 0; k < 128; ++k) s += mr[k] * wq[k * 128 + j];
    W[e] = s * scale;
  }
  if (threadIdx.x < 128) {
    int i = threadIdx.x;
    float s = 0.f;
    const float* mr = mw + i * 128;
    for (int k = 0; k < 128; ++k) s += mr[k] * bq[k];
    bb[i] = (s + mb[i]) * scale;
  }
}

// ---------------- fused LN1 + q-proj + q~ + flash attention over raw tokens ----------------
// block = batch. thread: rp=tid>>3 (rows r0=2rp,r1=2rp+1 of 64=H*NL), kc=tid&7,
// dims handled = { kc*4 + u*32 + j : u<4, j<4 }  (conflict-free LDS swizzle).
__global__ __launch_bounds__(256) void attn_kernel(
    const float* __restrict__ Kp, const float* __restrict__ Vp,
    const int* __restrict__ seg_start, const int* __restrict__ seg_cnt,
    const float* __restrict__ lat,
    const float* __restrict__ lng, const float* __restrict__ lnb,
    const float* __restrict__ Wqf, const float* __restrict__ bqf,
    const float* __restrict__ wk, int maxlen,
    float* __restrict__ o_out) {
  __shared__ __align__(16) float smem[10496];
  float* sA  = smem;            // 4096: nl (phase0) / K tile
  float* sB  = smem + 4096;     // 4096: qh (phase0) / V tile
  float* sSV = smem + 8192;     // 64 x 33 scores/probs
  float* sM  = smem + 10304;    // 64
  float* sL  = smem + 10368;    // 64
  float* sAl = smem + 10432;    // 64

  const int tid = threadIdx.x;
  const int b = blockIdx.x;

  // Phase 0a: LayerNorm(lat rows) -> sA
  {
    int q = tid >> 4, li = tid & 15, d0 = li * 8;
    const float* xr = lat + ((size_t)b * NL + q) * DD + d0;
    float x[8];
    *(float4*)(x) = *(const float4*)(xr);
    *(float4*)(x + 4) = *(const float4*)(xr + 4);
    float s1 = 0.f, s2 = 0.f;
#pragma unroll
    for (int j = 0; j < 8; ++j) { s1 += x[j]; s2 += x[j] * x[j]; }
#pragma unroll
    for (int o = 1; o < 16; o <<= 1) { s1 += __shfl_xor(s1, o); s2 += __shfl_xor(s2, o); }
    float mean = s1 * (1.f / 128.f);
    float var = s2 * (1.f / 128.f) - mean * mean;
    float rstd = rsqrtf(var + 1e-5f);
#pragma unroll
    for (int j = 0; j < 8; ++j)
      sA[q * DD + d0 + j] = (x[j] - mean) * rstd * lng[d0 + j] + lnb[d0 + j];
  }
  __syncthreads();

  // Phase 0b: qh = nl @ Wqf^T + bqf  -> sB  (scale already folded)
  {
    int i = tid >> 1, kh = tid & 1;
    float a[16];
#pragma unroll
    for (int q = 0; q < 16; ++q) a[q] = 0.f;
    const float* wr = Wqf + i * DD + kh * 64;
    const float* nb = sA + kh * 64;
    for (int kk = 0; kk < 64; ++kk) {
      float w = wr[kk];
#pragma unroll
      for (int q = 0; q < 16; ++q) a[q] += w * nb[q * DD + kk];
    }
#pragma unroll
    for (int q = 0; q < 16; ++q) a[q] += __shfl_xor(a[q], 1);
    float bb = bqf[i];
#pragma unroll
    for (int q8 = 0; q8 < 8; ++q8) {
      int q = kh * 8 + q8;
      sB[q * DD + i] = a[q] + bb;
    }
  }
  if (tid < 64) { sM[tid] = -3.0e38f; sL[tid] = 0.f; }
  __syncthreads();

  // Phase 0c: per-thread q~ fragments: qt[r][d] = sum_j qh[q(r)][h*32+j] * wk[(h*32+j)*128+d]
  const int rp = tid >> 3;
  const int kc = tid & 7;
  const int r0 = rp * 2, r1 = r0 + 1;
  const int h = tid >> 6;  // == r0>>4 (wave == head)
  float qt0[16], qt1[16];
  {
#pragma unroll
    for (int j = 0; j < 16; ++j) { qt0[j] = 0.f; qt1[j] = 0.f; }
    int q0 = r0 & 15, q1 = r1 & 15;
    const float* qh0 = sB + q0 * DD + h * HD;
    const float* qh1 = sB + q1 * DD + h * HD;
    const float* wkh = wk + (h * HD) * DD;
    for (int jj = 0; jj < 32; ++jj) {
      float a0 = qh0[jj];
      float a1 = qh1[jj];
      const float* wr = wkh + jj * DD + kc * 4;
#pragma unroll
      for (int u = 0; u < 4; ++u) {
        float4 w4 = *(const float4*)(wr + u * 32);
        qt0[u*4+0] += a0 * w4.x; qt0[u*4+1] += a0 * w4.y; qt0[u*4+2] += a0 * w4.z; qt0[u*4+3] += a0 * w4.w;
        qt1[u*4+0] += a1 * w4.x; qt1[u*4+1] += a1 * w4.y; qt1[u*4+2] += a1 * w4.z; qt1[u*4+3] += a1 * w4.w;
      }
    }
  }
  __syncthreads();  // qh reads done; tiles may overwrite sA/sB

  int n = seg_cnt[b]; if (n > maxlen) n = maxlen;
  const int st = seg_start[b];

  float acc0[16], acc1[16];
#pragma unroll
  for (int j = 0; j < 16; ++j) { acc0[j] = 0.f; acc1[j] = 0.f; }

  for (int t0 = 0; t0 < n; t0 += 32) {
    int nv = n - t0; if (nv > 32) nv = 32;
    // stage K/V tile (zero-fill invalid rows)
#pragma unroll
    for (int it = 0; it < 4; ++it) {
      int f = tid + it * 256;
      int row = f >> 5, c4 = f & 31;
      float4 kv = {0.f,0.f,0.f,0.f}, vv = {0.f,0.f,0.f,0.f};
      if (row < nv) {
        size_t g = ((size_t)(st + t0 + row)) * DD + c4 * 4;
        kv = *(const float4*)(Kp + g);
        vv = *(const float4*)(Vp + g);
      }
      *(float4*)(sA + f * 4) = kv;
      *(float4*)(sB + f * 4) = vv;
    }
    __syncthreads();
    // scores
    for (int t = 0; t < nv; ++t) {
      const float* kr = sA + t * DD + kc * 4;
      float s0 = 0.f, s1 = 0.f;
#pragma unroll
      for (int u = 0; u < 4; ++u) {
        float4 k4 = *(const float4*)(kr + u * 32);
        s0 += qt0[u*4+0]*k4.x + qt0[u*4+1]*k4.y + qt0[u*4+2]*k4.z + qt0[u*4+3]*k4.w;
        s1 += qt1[u*4+0]*k4.x + qt1[u*4+1]*k4.y + qt1[u*4+2]*k4.z + qt1[u*4+3]*k4.w;
      }
      s0 += __shfl_xor(s0, 1); s0 += __shfl_xor(s0, 2); s0 += __shfl_xor(s0, 4);
      s1 += __shfl_xor(s1, 1); s1 += __shfl_xor(s1, 2); s1 += __shfl_xor(s1, 4);
      if (kc == 0) sSV[r0 * 33 + t] = s0;
      else if (kc == 1) sSV[r1 * 33 + t] = s1;
    }
    __syncthreads();
    // online softmax update (wave 0 only)
    if (tid < 64) {
      int r = tid;
      float mold = sM[r];
      float mt = mold;
      for (int t = 0; t < nv; ++t) mt = fmaxf(mt, sSV[r * 33 + t]);
      float al = __expf(mold - mt);
      float ps = 0.f;
      for (int t = 0; t < nv; ++t) {
        float p = __expf(sSV[r * 33 + t] - mt);
        sSV[r * 33 + t] = p;
        ps += p;
      }
      sL[r] = sL[r] * al + ps;
      sM[r] = mt;
      sAl[r] = al;
    }
    __syncthreads();
    // accumulate raw-V
    {
      float al0 = sAl[r0], al1 = sAl[r1];
#pragma unroll
      for (int j = 0; j < 16; ++j) { acc0[j] *= al0; acc1[j] *= al1; }
      for (int t = 0; t < nv; ++t) {
        float p0 = sSV[r0 * 33 + t];
        float p1 = sSV[r1 * 33 + t];
        const float* vr = sB + t * DD + kc * 4;
#pragma unroll
        for (int u = 0; u < 4; ++u) {
          float4 v4 = *(const float4*)(vr + u * 32);
          acc0[u*4+0] += p0*v4.x; acc0[u*4+1] += p0*v4.y; acc0[u*4+2] += p0*v4.z; acc0[u*4+3] += p0*v4.w;
          acc1[u*4+0] += p1*v4.x; acc1[u*4+1] += p1*v4.y; acc1[u*4+2] += p1*v4.z; acc1[u*4+3] += p1*v4.w;
        }
      }
    }
    __syncthreads();
  }

  float l0 = sL[r0], l1 = sL[r1];
  float inv0 = (l0 > 0.f) ? 1.f / l0 : 0.f;  // n==0 -> zeros -> post adds bv path exactly like ref
  float inv1 = (l1 > 0.f) ? 1.f / l1 : 0.f;
  float* out0 = o_out + ((size_t)b * 64 + r0) * DD + kc * 4;
  float* out1 = o_out + ((size_t)b * 64 + r1) * DD + kc * 4;
#pragma unroll
  for (int u = 0; u < 4; ++u) {
    float4 w0 = { acc0[u*4+0]*inv0, acc0[u*4+1]*inv0, acc0[u*4+2]*inv0, acc0[u*4+3]*inv0 };
    float4 w1 = { acc1[u*4+0]*inv1, acc1[u*4+1]*inv1, acc1[u*4+2]*inv1, acc1[u*4+3]*inv1 };
    *(float4*)(out0 + u * 32) = w0;
    *(float4*)(out1 + u * 32) = w1;
  }
}

// ---------------- wv/ow for both pathways + residual + LN2 + FFN ----------------
__global__ __launch_bounds__(256) void post_kernel(
    const float* __restrict__ od, const float* __restrict__ oe,
    const float* __restrict__ wv_d, const float* __restrict__ bv_d,
    const float* __restrict__ ow_d, const float* __restrict__ ob_d,
    const float* __restrict__ wv_e, const float* __restrict__ bv_e,
    const float* __restrict__ ow_e, const float* __restrict__ ob_e,
    const float* __restrict__ ln2g, const float* __restrict__ ln2b,
    const float* __restrict__ w1, const float* __restrict__ b1,
    const float* __restrict__ w2, const float* __restrict__ b2,
    float* __restrict__ lat) {
  __shared__ __align__(16) float sO[8192];    // o-tile stage; later [0..2047]=h1, [2048..6143]=f1
  __shared__ __align__(16) float sVH[2048];
  __shared__ __align__(16) float sAcc[2048];
  const int tid = threadIdx.x;
  const int b = blockIdx.x;

  // S1: stage o_d (64 rows x 128)
  {
    const float4* src = (const float4*)(od + (size_t)b * 8192);
#pragma unroll
    for (int it = 0; it < 8; ++it) ((float4*)sO)[tid + it * 256] = src[tid + it * 256];
  }
  __syncthreads();
  // S2: vh_d[q][i] = wv_d[i]·oD[h(i)*16+q] + bv_d[i]
  {
    int i = tid >> 1, kh = tid & 1, hh = i >> 5;
    float a[16];
#pragma unroll
    for (int q = 0; q < 16; ++q) a[q] = 0.f;
    const float* wr = wv_d + i * 128 + kh * 64;
    const float* xb = sO + (hh * 16) * 128 + kh * 64;
    for (int kk = 0; kk < 64; ++kk) {
      float w = wr[kk];
#pragma unroll
      for (int q = 0; q < 16; ++q) a[q] += w * xb[q * 128 + kk];
    }
#pragma unroll
    for (int q = 0; q < 16; ++q) a[q] += __shfl_xor(a[q], 1);
    float bb = bv_d[i];
#pragma unroll
    for (int q8 = 0; q8 < 8; ++q8) { int q = kh * 8 + q8; sVH[q * 128 + i] = a[q] + bb; }
  }
  __syncthreads();
  // S3: acc = lat + ow_d·vh_d + ob_d ; then stage o_e
  {
    int i = tid >> 1, kh = tid & 1;
    float a[16];
#pragma unroll
    for (int q = 0; q < 16; ++q) a[q] = 0.f;
    const float* wr = ow_d + i * 128 + kh * 64;
    const float* xb = sVH + kh * 64;
    for (int kk = 0; kk < 64; ++kk) {
      float w = wr[kk];
#pragma unroll
      for (int q = 0; q < 16; ++q) a[q] += w * xb[q * 128 + kk];
    }
#pragma unroll
    for (int q = 0; q < 16; ++q) a[q] += __shfl_xor(a[q], 1);
    float bb = ob_d[i];
#pragma unroll
    for (int q8 = 0; q8 < 8; ++q8) {
      int q = kh * 8 + q8;
      sAcc[q * 128 + i] = lat[((size_t)b * 16 + q) * 128 + i] + a[q] + bb;
    }
  }
  {
    const float4* src = (const float4*)(oe + (size_t)b * 8192);
#pragma unroll
    for (int it = 0; it < 8; ++it) ((float4*)sO)[tid + it * 256] = src[tid + it * 256];
  }
  __syncthreads();
  // S5: vh_e
  {
    int i = tid >> 1, kh = tid & 1, hh = i >> 5;
    float a[16];
#pragma unroll
    for (int q = 0; q < 16; ++q) a[q] = 0.f;
    const float* wr = wv_e + i * 128 + kh * 64;
    const float* xb = sO + (hh * 16) * 128 + kh * 64;
    for (int kk = 0; kk < 64; ++kk) {
      float w = wr[kk];
#pragma unroll
      for (int q = 0; q < 16; ++q) a[q] += w * xb[q * 128 + kk];
    }
#pragma unroll
    for (int q = 0; q < 16; ++q) a[q] += __shfl_xor(a[q], 1);
    float bb = bv_e[i];
#pragma unroll
    for (int q8 = 0; q8 < 8; ++q8) { int q = kh * 8 + q8; sVH[q * 128 + i] = a[q] + bb; }
  }
  __syncthreads();
  // S6: acc += ow_e·vh_e + ob_e
  {
    int i = tid >> 1, kh = tid & 1;
    float a[16];
#pragma unroll
    for (int q = 0; q < 16; ++q) a[q] = 0.f;
    const float* wr = ow_e + i * 128 + kh * 64;
    const float* xb = sVH + kh * 64;
    for (int kk = 0; kk < 64; ++kk) {
      float w = wr[kk];
#pragma unroll
      for (int q = 0; q < 16; ++q) a[q] += w * xb[q * 128 + kk];
    }
#pragma unroll
    for (int q = 0; q < 16; ++q) a[q] += __shfl_xor(a[q], 1);
    float bb = ob_e[i];
#pragma unroll
    for (int q8 = 0; q8 < 8; ++q8) { int q = kh * 8 + q8; sAcc[q * 128 + i] += a[q] + bb; }
  }
  __syncthreads();
  // S7: LN2 -> sO[0..2047]
  {
    int q = tid >> 4, li = tid & 15, d0 = li * 8;
    float x[8];
#pragma unroll
    for (int j = 0; j < 8; ++j) x[j] = sAcc[q * 128 + d0 + j];
    float s1 = 0.f, s2 = 0.f;
#pragma unroll
    for (int j = 0; j < 8; ++j) { s1 += x[j]; s2 += x[j] * x[j]; }
#pragma unroll
    for (int o = 1; o < 16; o <<= 1) { s1 += __shfl_xor(s1, o); s2 += __shfl_xor(s2, o); }
    float mean = s1 * (1.f / 128.f);
    float var = s2 * (1.f / 128.f) - mean * mean;
    float rstd = rsqrtf(var + 1e-5f);
#pragma unroll
    for (int j = 0; j < 8; ++j)
      sO[q * 128 + d0 + j] = (x[j] - mean) * rstd * ln2g[d0 + j] + ln2b[d0 + j];
  }
  __syncthreads();
  // S8: f1 = relu(h1 @ w1^T + b1) -> sO[2048 + q*256 + o]
  {
    int o = tid;
    float a[16];
#pragma unroll
    for (int q = 0; q < 16; ++q) a[q] = 0.f;
    const float* wr = w1 + o * 128;
    for (int k = 0; k < 128; ++k) {
      float w = wr[k];
#pragma unroll
      for (int q = 0; q < 16; ++q) a[q] += w * sO[q * 128 + k];
    }
    float bb = b1[o];
#pragma unroll
    for (int q = 0; q < 16; ++q) sO[2048 + q * 256 + o] = fmaxf(a[q] + bb, 0.f);
  }
  __syncthreads();
  // S9: lat = acc + f1 @ w2^T + b2
  {
    int i = tid >> 1, kh = tid & 1;
    float a[16];
#pragma unroll
    for (int q = 0; q < 16; ++q) a[q] = 0.f;
    const float* wr = w2 + i * 256 + kh * 128;
    const float* xb = sO + 2048 + kh * 128;
    for (int kk = 0; kk < 128; ++kk) {
      float w = wr[kk];
#pragma unroll
      for (int q = 0; q < 16; ++q) a[q] += w * xb[q * 256 + kk];
    }
#pragma unroll
    for (int q = 0; q < 16; ++q) a[q] += __shfl_xor(a[q], 1);
    float bb = b2[i];
#pragma unroll
    for (int q8 = 0; q8 < 8; ++q8) {
      int q = kh * 8 + q8;
      lat[((size_t)b * 16 + q) * 128 + i] = sAcc[q * 128 + i] + a[q] + bb;
    }
  }
}

// ---------------- head: relu(flat @ w1^T + b1) @ w2^T + b2 -> softplus ----------------
__global__ __launch_bounds__(256) void head_kernel(const float* __restrict__ lat,
                                                   const float* __restrict__ w1,
                                                   const float* __restrict__ b1,
                                                   const float* __restrict__ w2,
                                                   const float* __restrict__ b2,
                                                   float* __restrict__ out) {
  __shared__ __align__(16) float sX[2048];
  __shared__ float sH[128];
  const int tid = threadIdx.x;
  const int b = blockIdx.x;
  {
    const float4* src = (const float4*)(lat + (size_t)b * 2048);
#pragma unroll
    for (int it = 0; it < 2; ++it) ((float4*)sX)[tid + it * 256] = src[tid + it * 256];
  }
  __syncthreads();
  {
    int o = tid >> 1, kh = tid & 1;
    float a = 0.f;
    const float* wr = w1 + (size_t)o * 2048 + kh * 1024;
    const float* xb = sX + kh * 1024;
    for (int kk = 0; kk < 1024; ++kk) a += wr[kk] * xb[kk];
    a += __shfl_xor(a, 1);
    if (kh == 0) sH[o] = fmaxf(a + b1[o], 0.f);
  }
  __syncthreads();
  if (tid < 64) {
    float a = sH[tid] * w2[tid] + sH[tid + 64] * w2[tid + 64];
#pragma unroll
    for (int o = 1; o < 64; o <<= 1) a += __shfl_xor(a, o);
    if (tid == 0) {
      float x = a + b2[0];
      out[b] = (x > 20.f) ? x : log1pf(__expf(x));
    }
  }
}

extern "C" void kernel_launch(void* const* d_in, const int* in_sizes, int n_in,
                              void* d_out, int out_size, void* d_ws, size_t ws_size,
                              hipStream_t stream) {
  const float* drug_k  = (const float*)d_in[0];
  const float* drug_v  = (const float*)d_in[1];
  const float* enz_k   = (const float*)d_in[2];
  const float* enz_v   = (const float*)d_in[3];
  const int*   drug_b  = (const int*)d_in[4];
  const int*   enz_b   = (const int*)d_in[5];
  const float* latents = (const float*)d_in[6];
  const float* wq_d    = (const float*)d_in[7];
  const float* bq_d    = (const float*)d_in[8];
  const float* wq_e    = (const float*)d_in[9];
  const float* bq_e    = (const float*)d_in[10];
  const float* mha_d_w = (const float*)d_in[11];
  const float* mha_d_b = (const float*)d_in[12];
  const float* mha_d_ow= (const float*)d_in[13];
  const float* mha_d_ob= (const float*)d_in[14];
  const float* mha_e_w = (const float*)d_in[15];
  const float* mha_e_b = (const float*)d_in[16];
  const float* mha_e_ow= (const float*)d_in[17];
  const float* mha_e_ob= (const float*)d_in[18];
  const float* ln1_g   = (const float*)d_in[19];
  const float* ln1_b   = (const float*)d_in[20];
  const float* ln2_g   = (const float*)d_in[21];
  const float* ln2_b   = (const float*)d_in[22];
  const float* ffn_w1  = (const float*)d_in[23];
  const float* ffn_b1  = (const float*)d_in[24];
  const float* ffn_w2  = (const float*)d_in[25];
  const float* ffn_b2  = (const float*)d_in[26];
  const float* head_w1 = (const float*)d_in[27];
  const float* head_b1 = (const float*)d_in[28];
  const float* head_w2 = (const float*)d_in[29];
  const float* head_b2 = (const float*)d_in[30];
  float* out = (float*)d_out;

  // workspace layout (floats): seg(2048 ints) | Wqf 8*16384 | bqf 8*128 | lat 512*2048 | o_d 512*64*128 | o_e
  int* seg = (int*)d_ws;
  float* fws = (float*)d_ws;
  float* Wqf = fws + 2048;
  float* bqf = Wqf + 131072;
  float* lat = bqf + 1024;
  float* o_d = lat + 1048576;
  float* o_e = o_d + 4194304;   // total ~38.3 MB

  seg_kernel<<<2, 512, 0, stream>>>(drug_b, in_sizes[4], enz_b, in_sizes[5], seg);
  init_lat_kernel<<<4096, 256, 0, stream>>>(latents, lat);
  fold_kernel<<<8, 256, 0, stream>>>(wq_d, bq_d, wq_e, bq_e,
                                     mha_d_w, mha_d_b, mha_e_w, mha_e_b, Wqf, bqf);
  for (int l = 0; l < 4; ++l) {
    const float* mwd = mha_d_w + (size_t)l * 49152;
    const float* mbd = mha_d_b + l * 384;
    const float* mwe = mha_e_w + (size_t)l * 49152;
    const float* mbe = mha_e_b + l * 384;
    attn_kernel<<<512, 256, 0, stream>>>(drug_k, drug_v, seg, seg + 512, lat,
        ln1_g + l * 128, ln1_b + l * 128,
        Wqf + (size_t)(l * 2 + 0) * 16384, bqf + (l * 2 + 0) * 128,
        mwd + 16384, 128, o_d);
    attn_kernel<<<512, 256, 0, stream>>>(enz_k, enz_v, seg + 1024, seg + 1536, lat,
        ln1_g + l * 128, ln1_b + l * 128,
        Wqf + (size_t)(l * 2 + 1) * 16384, bqf + (l * 2 + 1) * 128,
        mwe + 16384, 512, o_e);
    post_kernel<<<512, 256, 0, stream>>>(o_d, o_e,
        mwd + 32768, mbd + 256, mha_d_ow + (size_t)l * 16384, mha_d_ob + l * 128,
        mwe + 32768, mbe + 256, mha_e_ow + (size_t)l * 16384, mha_e_ob + l * 128,
        ln2_g + l * 128, ln2_b + l * 128,
        ffn_w1 + (size_t)l * 32768, ffn_b1 + l * 256,
        ffn_w2 + (size_t)l * 32768, ffn_b2 + l * 128,
        lat);
  }
  head_kernel<<<512, 256, 0, stream>>>(lat, head_w1, head_b1, head_w2, head_b2, out);
}

// Round 2
// 1324.908 us; speedup vs baseline: 1.4998x; 1.4998x over previous
//
#include <hip/hip_runtime.h>
#include <math.h>

#define NBATCH 512
#define NL 16
#define DD 128
#define HH 4
#define HD 32

typedef __attribute__((ext_vector_type(8))) short short8;
typedef __attribute__((ext_vector_type(4))) float floatx4;

__device__ __forceinline__ unsigned short f2bf(float x) {
  union { float f; unsigned u; } v; v.f = x; return (unsigned short)(v.u >> 16);
}
__device__ __forceinline__ float bf2f(unsigned short s) {
  union { unsigned u; float f; } v; v.u = ((unsigned)s) << 16; return v.f;
}

// ---------------- segment table (batch arrays are sorted) ----------------
__global__ void seg_kernel(const int* __restrict__ db, int nd,
                           const int* __restrict__ eb, int ne,
                           int* __restrict__ seg) {
  const int* arr = (blockIdx.x == 0) ? db : eb;
  int n = (blockIdx.x == 0) ? nd : ne;
  int* start = seg + blockIdx.x * 1024;
  int* cnt = start + 512;
  int b = threadIdx.x;
  if (b < 512) {
    int lo = 0, hi = n;
    while (lo < hi) { int mid = (lo + hi) >> 1; if (arr[mid] < b) lo = mid + 1; else hi = mid; }
    int s = lo;
    lo = s; hi = n;
    while (lo < hi) { int mid = (lo + hi) >> 1; if (arr[mid] < b + 1) lo = mid + 1; else hi = mid; }
    start[b] = s; cnt[b] = lo - s;
  }
}

// ---------------- lat init ----------------
__global__ void init_lat_kernel(const float* __restrict__ latents, float* __restrict__ lat) {
  int i = blockIdx.x * blockDim.x + threadIdx.x;
  lat[i] = latents[i & 2047];
}

// ---------------- fold: Wqf = mwq @ wq (scaled), bqf = (mwq@bq + mbq) scaled ----------------
__global__ void fold_kernel(const float* __restrict__ wq_d, const float* __restrict__ bq_d,
                            const float* __restrict__ wq_e, const float* __restrict__ bq_e,
                            const float* __restrict__ mw_d, const float* __restrict__ mb_d,
                            const float* __restrict__ mw_e, const float* __restrict__ mb_e,
                            float* __restrict__ Wqf, float* __restrict__ bqf) {
  int l = blockIdx.x >> 1, p = blockIdx.x & 1;
  const float* wq = (p == 0 ? wq_d : wq_e) + l * 16384;
  const float* bq = (p == 0 ? bq_d : bq_e) + l * 128;
  const float* mw = (p == 0 ? mw_d : mw_e) + (size_t)l * 49152;
  const float* mb = (p == 0 ? mb_d : mb_e) + l * 384;
  float* W = Wqf + (size_t)blockIdx.x * 16384;
  float* bb = bqf + blockIdx.x * 128;
  const float scale = 0.17677669529663687f;  // 1/sqrt(32)
  for (int e = threadIdx.x; e < 16384; e += blockDim.x) {
    int i = e >> 7, j = e & 127;
    float s = 0.f;
    const float* mr = mw + i * 128;
    for (int k = 0; k < 128; ++k) s += mr[k] * wq[k * 128 + j];
    W[e] = s * scale;
  }
  if (threadIdx.x < 128) {
    int i = threadIdx.x;
    float s = 0.f;
    const float* mr = mw + i * 128;
    for (int k = 0; k < 128; ++k) s += mr[k] * bq[k];
    bb[i] = (s + mb[i]) * scale;
  }
}

// ---------------- per-layer Q~ precompute: LN1 + qh (both paths) + wk fold -> bf16 ----------------
__global__ __launch_bounds__(256) void qtilde_kernel(
    const float* __restrict__ lat,
    const float* __restrict__ lng, const float* __restrict__ lnb,
    const float* __restrict__ Wqf2, const float* __restrict__ bqf2,
    const float* __restrict__ wk_d, const float* __restrict__ wk_e,
    unsigned short* __restrict__ Qt) {
  __shared__ __align__(16) float sNL[2048];
  __shared__ __align__(16) float sQH[2][16 * 132];
  const int tid = threadIdx.x;
  const int b = blockIdx.x;
  // LN1
  {
    int q = tid >> 4, li = tid & 15, d0 = li * 8;
    const float* xr = lat + ((size_t)b * NL + q) * DD + d0;
    float x[8];
    *(float4*)(x) = *(const float4*)(xr);
    *(float4*)(x + 4) = *(const float4*)(xr + 4);
    float s1 = 0.f, s2 = 0.f;
#pragma unroll
    for (int j = 0; j < 8; ++j) { s1 += x[j]; s2 += x[j] * x[j]; }
#pragma unroll
    for (int o = 1; o < 16; o <<= 1) { s1 += __shfl_xor(s1, o); s2 += __shfl_xor(s2, o); }
    float mean = s1 * (1.f / 128.f);
    float var = s2 * (1.f / 128.f) - mean * mean;
    float rstd = rsqrtf(var + 1e-5f);
#pragma unroll
    for (int j = 0; j < 8; ++j)
      sNL[q * DD + d0 + j] = (x[j] - mean) * rstd * lng[d0 + j] + lnb[d0 + j];
  }
  __syncthreads();
  // qh[p][q][i] = nl @ Wqf^T + bqf
  {
    int p = tid >> 7, i = tid & 127;
    const float* wr = Wqf2 + p * 16384 + i * 128;
    float a[16];
#pragma unroll
    for (int q = 0; q < 16; ++q) a[q] = 0.f;
    for (int k4 = 0; k4 < 32; ++k4) {
      float4 w4 = *(const float4*)(wr + k4 * 4);
      int k = k4 * 4;
#pragma unroll
      for (int q = 0; q < 16; ++q)
        a[q] += w4.x * sNL[q * 128 + k] + w4.y * sNL[q * 128 + k + 1]
              + w4.z * sNL[q * 128 + k + 2] + w4.w * sNL[q * 128 + k + 3];
    }
    float bb = bqf2[p * 128 + i];
#pragma unroll
    for (int q = 0; q < 16; ++q) sQH[p][q * 132 + i] = a[q] + bb;
  }
  __syncthreads();
  // q~[(p,h,q)][d] = sum_j qh[p][q][h*32+j] * wk_p[h*32+j][d]  -> bf16
  {
    int rowp = tid >> 1, dh = tid & 1;
    int p = rowp >> 6, r = rowp & 63, h = r >> 4, q = r & 15;
    const float* wkp = (p == 0 ? wk_d : wk_e) + (h * 32) * 128;
    float qv[32];
#pragma unroll
    for (int j = 0; j < 32; ++j) qv[j] = sQH[p][q * 132 + h * 32 + j];
    unsigned short* outp = Qt + (((size_t)b * 2 + p) * 64 + r) * 128;
#pragma unroll
    for (int db = 0; db < 2; ++db) {
      int d0 = dh * 64 + db * 32;
      float acc[32];
#pragma unroll
      for (int d = 0; d < 32; ++d) acc[d] = 0.f;
      for (int j = 0; j < 32; ++j) {
        float qvj = qv[j];
        const float* wrow = wkp + j * 128 + d0;
#pragma unroll
        for (int d4 = 0; d4 < 8; ++d4) {
          float4 w4 = *(const float4*)(wrow + d4 * 4);
          acc[d4*4+0] += qvj * w4.x; acc[d4*4+1] += qvj * w4.y;
          acc[d4*4+2] += qvj * w4.z; acc[d4*4+3] += qvj * w4.w;
        }
      }
#pragma unroll
      for (int u = 0; u < 8; ++u) {
        ushort4 o4 = { f2bf(acc[u*4]), f2bf(acc[u*4+1]), f2bf(acc[u*4+2]), f2bf(acc[u*4+3]) };
        *(ushort4*)(outp + d0 + u * 4) = o4;
      }
    }
  }
}

// ---------------- MFMA flash attention (no-max online softmax, split tokens) ----------------
// wave w handles rows [16w,16w+16) (head w). Writes bf16 partial acc + fp32 l per split.
__global__ __launch_bounds__(256, 4) void attn2_kernel(
    const float* __restrict__ Kp, const float* __restrict__ Vp,
    const int* __restrict__ seg_start, const int* __restrict__ seg_cnt,
    const unsigned short* __restrict__ Qt, int qt_stride,
    int maxlen, int nsl,
    unsigned short* __restrict__ part, float* __restrict__ lpart) {
  __shared__ __align__(16) unsigned short sK[32 * 136];  // row stride 272B: conflict-free frag reads
  __shared__ __align__(16) unsigned short sV[128 * 40];  // [dim][token], stride 80B
  __shared__ __align__(16) unsigned short sP[64 * 40];   // wave-private P, stride 80B
  const int tid = threadIdx.x;
  const int nsplit = 1 << nsl;
  const int b = blockIdx.x >> nsl;
  const int sp = blockIdx.x & (nsplit - 1);
  int n = seg_cnt[b]; if (n > maxlen) n = maxlen;
  const int chunk = (n + nsplit - 1) >> nsl;
  const int begin = sp * chunk;
  int len = n - begin; if (len > chunk) len = chunk; if (len < 0) len = 0;
  const int st = seg_start[b] + begin;

  const int lane = tid & 63;
  const int w = tid >> 6;
  const int m = lane & 15;
  const int quad = lane >> 4;

  // A-frags: q~ rows of this wave (A[m][k=c*32+quad*8+j])
  short8 qA[4];
  {
    const unsigned short* qrow = Qt + (size_t)b * qt_stride + (size_t)(w * 16 + m) * 128 + quad * 8;
#pragma unroll
    for (int c = 0; c < 4; ++c) qA[c] = *(const short8*)(qrow + c * 32);
  }

  floatx4 oA[8];
#pragma unroll
  for (int i = 0; i < 8; ++i) oA[i] = (floatx4){0.f, 0.f, 0.f, 0.f};
  float lp[4] = {0.f, 0.f, 0.f, 0.f};

  float4 rK[4], rV[4];
  auto load_tile = [&](int t0) {
    int nv = len - t0; if (nv > 32) nv = 32;
#pragma unroll
    for (int it = 0; it < 4; ++it) {
      int f = tid + it * 256;
      int tok = f >> 5, seg = f & 31;
      rK[it] = (tok < nv) ? *(const float4*)(Kp + (size_t)(st + t0 + tok) * 128 + seg * 4)
                          : (float4){0.f, 0.f, 0.f, 0.f};
    }
#pragma unroll
    for (int it = 0; it < 4; ++it) {
      int f = tid + it * 256;
      int tok = f & 31, seg = f >> 5;
      rV[it] = (tok < nv) ? *(const float4*)(Vp + (size_t)(st + t0 + tok) * 128 + seg * 4)
                          : (float4){0.f, 0.f, 0.f, 0.f};
    }
  };
  auto store_tile = [&]() {
#pragma unroll
    for (int it = 0; it < 4; ++it) {
      int f = tid + it * 256;
      int tok = f >> 5, seg = f & 31;
      ushort4 u = { f2bf(rK[it].x), f2bf(rK[it].y), f2bf(rK[it].z), f2bf(rK[it].w) };
      *(ushort4*)(sK + tok * 136 + seg * 4) = u;
    }
#pragma unroll
    for (int it = 0; it < 4; ++it) {
      int f = tid + it * 256;
      int tok = f & 31, seg = f >> 5;
      int d0 = seg * 4;
      sV[(d0 + 0) * 40 + tok] = f2bf(rV[it].x);
      sV[(d0 + 1) * 40 + tok] = f2bf(rV[it].y);
      sV[(d0 + 2) * 40 + tok] = f2bf(rV[it].z);
      sV[(d0 + 3) * 40 + tok] = f2bf(rV[it].w);
    }
  };

  if (len > 0) load_tile(0);
  for (int t0 = 0; t0 < len; t0 += 32) {
    __syncthreads();
    store_tile();
    __syncthreads();
    if (t0 + 32 < len) load_tile(t0 + 32);
    int nv = len - t0; if (nv > 32) nv = 32;
    // S = Q~ @ K^T  (two 16-token column tiles)
    floatx4 sS[2];
    sS[0] = (floatx4){0.f, 0.f, 0.f, 0.f};
    sS[1] = (floatx4){0.f, 0.f, 0.f, 0.f};
#pragma unroll
    for (int g = 0; g < 2; ++g)
#pragma unroll
      for (int c = 0; c < 4; ++c) {
        short8 kB = *(const short8*)(sK + (g * 16 + m) * 136 + c * 32 + quad * 8);
        sS[g] = __builtin_amdgcn_mfma_f32_16x16x32_bf16(qA[c], kB, sS[g], 0, 0, 0);
      }
    // P = exp(S) (no max-shift: |s| << 1 by construction), mask tail, accumulate l
#pragma unroll
    for (int g = 0; g < 2; ++g) {
      bool valid = (g * 16 + m) < nv;
#pragma unroll
      for (int r = 0; r < 4; ++r) {
        float p = valid ? __expf(sS[g][r]) : 0.f;
        lp[r] += p;
        sP[(w * 16 + quad * 4 + r) * 40 + g * 16 + m] = f2bf(p);
      }
    }
    // PV: o += P @ V   (P via wave-private LDS round-trip to A-layout)
    short8 pA = *(const short8*)(sP + (w * 16 + m) * 40 + quad * 8);
#pragma unroll
    for (int dg = 0; dg < 8; ++dg) {
      short8 vB = *(const short8*)(sV + (dg * 16 + m) * 40 + quad * 8);
      oA[dg] = __builtin_amdgcn_mfma_f32_16x16x32_bf16(pA, vB, oA[dg], 0, 0, 0);
    }
  }

  // reduce l across the 16 token-columns
#pragma unroll
  for (int r = 0; r < 4; ++r) {
    float v = lp[r];
    v += __shfl_xor(v, 1); v += __shfl_xor(v, 2);
    v += __shfl_xor(v, 4); v += __shfl_xor(v, 8);
    lp[r] = v;
  }
  const size_t pb = ((size_t)b << nsl) + sp;
  if (m == 0) {
#pragma unroll
    for (int r = 0; r < 4; ++r)
      lpart[pb * 64 + w * 16 + quad * 4 + r] = lp[r];
  }
  unsigned short* pout = part + pb * 8192;
#pragma unroll
  for (int dg = 0; dg < 8; ++dg)
#pragma unroll
    for (int r = 0; r < 4; ++r)
      pout[(w * 16 + quad * 4 + r) * 128 + dg * 16 + m] = f2bf(oA[dg][r]);
}

// ---------------- combine partials + wv/ow + residual + LN2 + FFN ----------------
__global__ __launch_bounds__(256) void post_kernel(
    const unsigned short* __restrict__ pd, const float* __restrict__ ldv,
    const unsigned short* __restrict__ pe, const float* __restrict__ lev,
    const float* __restrict__ wv_d, const float* __restrict__ bv_d,
    const float* __restrict__ ow_d, const float* __restrict__ ob_d,
    const float* __restrict__ wv_e, const float* __restrict__ bv_e,
    const float* __restrict__ ow_e, const float* __restrict__ ob_e,
    const float* __restrict__ ln2g, const float* __restrict__ ln2b,
    const float* __restrict__ w1, const float* __restrict__ b1,
    const float* __restrict__ w2, const float* __restrict__ b2,
    float* __restrict__ lat) {
  __shared__ __align__(16) float sO[8192];
  __shared__ __align__(16) float sVH[2048];
  __shared__ __align__(16) float sAcc[2048];
  __shared__ float sLd[64], sLe[64];
  const int tid = threadIdx.x;
  const int b = blockIdx.x;

  if (tid < 64) {
    float v = ldv[(size_t)b * 64 + tid];
    sLd[tid] = (v > 0.f) ? 1.f / v : 0.f;
  } else if (tid < 128) {
    int r = tid - 64;
    float v = lev[((size_t)b * 2) * 64 + r] + lev[((size_t)b * 2 + 1) * 64 + r];
    sLe[r] = (v > 0.f) ? 1.f / v : 0.f;
  }
  __syncthreads();
  // S1: drug o normalized -> sO
  {
    const unsigned short* src = pd + (size_t)b * 8192;
#pragma unroll
    for (int it = 0; it < 8; ++it) {
      int idx = tid + it * 256;
      ushort4 u = *(const ushort4*)(src + idx * 4);
      float sc = sLd[idx >> 5];
      sO[idx * 4 + 0] = bf2f(u.x) * sc;
      sO[idx * 4 + 1] = bf2f(u.y) * sc;
      sO[idx * 4 + 2] = bf2f(u.z) * sc;
      sO[idx * 4 + 3] = bf2f(u.w) * sc;
    }
  }
  __syncthreads();
  // S2: vh_d
  {
    int i = tid >> 1, kh = tid & 1, hh = i >> 5;
    float a[16];
#pragma unroll
    for (int q = 0; q < 16; ++q) a[q] = 0.f;
    const float* wr = wv_d + i * 128 + kh * 64;
    const float* xb = sO + (hh * 16) * 128 + kh * 64;
    for (int k4 = 0; k4 < 16; ++k4) {
      float4 w4 = *(const float4*)(wr + k4 * 4);
      int kk = k4 * 4;
#pragma unroll
      for (int q = 0; q < 16; ++q)
        a[q] += w4.x * xb[q*128+kk] + w4.y * xb[q*128+kk+1]
              + w4.z * xb[q*128+kk+2] + w4.w * xb[q*128+kk+3];
    }
#pragma unroll
    for (int q = 0; q < 16; ++q) a[q] += __shfl_xor(a[q], 1);
    float bb = bv_d[i];
#pragma unroll
    for (int q8 = 0; q8 < 8; ++q8) { int q = kh * 8 + q8; sVH[q * 128 + i] = a[q] + bb; }
  }
  __syncthreads();
  // S3: acc = lat + ow_d·vh_d + ob_d ; then stage combined enzyme o into sO
  {
    int i = tid >> 1, kh = tid & 1;
    float a[16];
#pragma unroll
    for (int q = 0; q < 16; ++q) a[q] = 0.f;
    const float* wr = ow_d + i * 128 + kh * 64;
    const float* xb = sVH + kh * 64;
    for (int k4 = 0; k4 < 16; ++k4) {
      float4 w4 = *(const float4*)(wr + k4 * 4);
      int kk = k4 * 4;
#pragma unroll
      for (int q = 0; q < 16; ++q)
        a[q] += w4.x * xb[q*128+kk] + w4.y * xb[q*128+kk+1]
              + w4.z * xb[q*128+kk+2] + w4.w * xb[q*128+kk+3];
    }
#pragma unroll
    for (int q = 0; q < 16; ++q) a[q] += __shfl_xor(a[q], 1);
    float bb = ob_d[i];
#pragma unroll
    for (int q8 = 0; q8 < 8; ++q8) {
      int q = kh * 8 + q8;
      sAcc[q * 128 + i] = lat[((size_t)b * 16 + q) * 128 + i] + a[q] + bb;
    }
  }
  {
    const unsigned short* s0 = pe + (size_t)(b * 2) * 8192;
    const unsigned short* s1 = pe + (size_t)(b * 2 + 1) * 8192;
#pragma unroll
    for (int it = 0; it < 8; ++it) {
      int idx = tid + it * 256;
      ushort4 u0 = *(const ushort4*)(s0 + idx * 4);
      ushort4 u1 = *(const ushort4*)(s1 + idx * 4);
      float sc = sLe[idx >> 5];
      sO[idx * 4 + 0] = (bf2f(u0.x) + bf2f(u1.x)) * sc;
      sO[idx * 4 + 1] = (bf2f(u0.y) + bf2f(u1.y)) * sc;
      sO[idx * 4 + 2] = (bf2f(u0.z) + bf2f(u1.z)) * sc;
      sO[idx * 4 + 3] = (bf2f(u0.w) + bf2f(u1.w)) * sc;
    }
  }
  __syncthreads();
  // S5: vh_e
  {
    int i = tid >> 1, kh = tid & 1, hh = i >> 5;
    float a[16];
#pragma unroll
    for (int q = 0; q < 16; ++q) a[q] = 0.f;
    const float* wr = wv_e + i * 128 + kh * 64;
    const float* xb = sO + (hh * 16) * 128 + kh * 64;
    for (int k4 = 0; k4 < 16; ++k4) {
      float4 w4 = *(const float4*)(wr + k4 * 4);
      int kk = k4 * 4;
#pragma unroll
      for (int q = 0; q < 16; ++q)
        a[q] += w4.x * xb[q*128+kk] + w4.y * xb[q*128+kk+1]
              + w4.z * xb[q*128+kk+2] + w4.w * xb[q*128+kk+3];
    }
#pragma unroll
    for (int q = 0; q < 16; ++q) a[q] += __shfl_xor(a[q], 1);
    float bb = bv_e[i];
#pragma unroll
    for (int q8 = 0; q8 < 8; ++q8) { int q = kh * 8 + q8; sVH[q * 128 + i] = a[q] + bb; }
  }
  __syncthreads();
  // S6: acc += ow_e·vh_e + ob_e
  {
    int i = tid >> 1, kh = tid & 1;
    float a[16];
#pragma unroll
    for (int q = 0; q < 16; ++q) a[q] = 0.f;
    const float* wr = ow_e + i * 128 + kh * 64;
    const float* xb = sVH + kh * 64;
    for (int k4 = 0; k4 < 16; ++k4) {
      float4 w4 = *(const float4*)(wr + k4 * 4);
      int kk = k4 * 4;
#pragma unroll
      for (int q = 0; q < 16; ++q)
        a[q] += w4.x * xb[q*128+kk] + w4.y * xb[q*128+kk+1]
              + w4.z * xb[q*128+kk+2] + w4.w * xb[q*128+kk+3];
    }
#pragma unroll
    for (int q = 0; q < 16; ++q) a[q] += __shfl_xor(a[q], 1);
    float bb = ob_e[i];
#pragma unroll
    for (int q8 = 0; q8 < 8; ++q8) { int q = kh * 8 + q8; sAcc[q * 128 + i] += a[q] + bb; }
  }
  __syncthreads();
  // S7: LN2 -> sO[0..2047]
  {
    int q = tid >> 4, li = tid & 15, d0 = li * 8;
    float x[8];
#pragma unroll
    for (int j = 0; j < 8; ++j) x[j] = sAcc[q * 128 + d0 + j];
    float s1 = 0.f, s2 = 0.f;
#pragma unroll
    for (int j = 0; j < 8; ++j) { s1 += x[j]; s2 += x[j] * x[j]; }
#pragma unroll
    for (int o = 1; o < 16; o <<= 1) { s1 += __shfl_xor(s1, o); s2 += __shfl_xor(s2, o); }
    float mean = s1 * (1.f / 128.f);
    float var = s2 * (1.f / 128.f) - mean * mean;
    float rstd = rsqrtf(var + 1e-5f);
#pragma unroll
    for (int j = 0; j < 8; ++j)
      sO[q * 128 + d0 + j] = (x[j] - mean) * rstd * ln2g[d0 + j] + ln2b[d0 + j];
  }
  __syncthreads();
  // S8: f1 = relu(h1 @ w1^T + b1)
  {
    int o = tid;
    float a[16];
#pragma unroll
    for (int q = 0; q < 16; ++q) a[q] = 0.f;
    const float* wr = w1 + o * 128;
    for (int k4 = 0; k4 < 32; ++k4) {
      float4 w4 = *(const float4*)(wr + k4 * 4);
      int k = k4 * 4;
#pragma unroll
      for (int q = 0; q < 16; ++q)
        a[q] += w4.x * sO[q*128+k] + w4.y * sO[q*128+k+1]
              + w4.z * sO[q*128+k+2] + w4.w * sO[q*128+k+3];
    }
    float bb = b1[o];
#pragma unroll
    for (int q = 0; q < 16; ++q) sO[2048 + q * 256 + o] = fmaxf(a[q] + bb, 0.f);
  }
  __syncthreads();
  // S9: lat = acc + f1 @ w2^T + b2
  {
    int i = tid >> 1, kh = tid & 1;
    float a[16];
#pragma unroll
    for (int q = 0; q < 16; ++q) a[q] = 0.f;
    const float* wr = w2 + i * 256 + kh * 128;
    const float* xb = sO + 2048 + kh * 128;
    for (int k4 = 0; k4 < 32; ++k4) {
      float4 w4 = *(const float4*)(wr + k4 * 4);
      int kk = k4 * 4;
#pragma unroll
      for (int q = 0; q < 16; ++q)
        a[q] += w4.x * xb[q*256+kk] + w4.y * xb[q*256+kk+1]
              + w4.z * xb[q*256+kk+2] + w4.w * xb[q*256+kk+3];
    }
#pragma unroll
    for (int q = 0; q < 16; ++q) a[q] += __shfl_xor(a[q], 1);
    float bb = b2[i];
#pragma unroll
    for (int q8 = 0; q8 < 8; ++q8) {
      int q = kh * 8 + q8;
      lat[((size_t)b * 16 + q) * 128 + i] = sAcc[q * 128 + i] + a[q] + bb;
    }
  }
}

// ---------------- head ----------------
__global__ __launch_bounds__(256) void head_kernel(const float* __restrict__ lat,
                                                   const float* __restrict__ w1,
                                                   const float* __restrict__ b1,
                                                   const float* __restrict__ w2,
                                                   const float* __restrict__ b2,
                                                   float* __restrict__ out) {
  __shared__ __align__(16) float sX[2048];
  __shared__ float sH[128];
  const int tid = threadIdx.x;
  const int b = blockIdx.x;
  {
    const float4* src = (const float4*)(lat + (size_t)b * 2048);
#pragma unroll
    for (int it = 0; it < 2; ++it) ((float4*)sX)[tid + it * 256] = src[tid + it * 256];
  }
  __syncthreads();
  {
    int o = tid >> 1, kh = tid & 1;
    float a = 0.f;
    const float* wr = w1 + (size_t)o * 2048 + kh * 1024;
    const float* xb = sX + kh * 1024;
    for (int k4 = 0; k4 < 256; ++k4) {
      float4 w4 = *(const float4*)(wr + k4 * 4);
      float4 x4 = *(const float4*)(xb + k4 * 4);
      a += w4.x * x4.x + w4.y * x4.y + w4.z * x4.z + w4.w * x4.w;
    }
    a += __shfl_xor(a, 1);
    if (kh == 0) sH[o] = fmaxf(a + b1[o], 0.f);
  }
  __syncthreads();
  if (tid < 64) {
    float a = sH[tid] * w2[tid] + sH[tid + 64] * w2[tid + 64];
#pragma unroll
    for (int o = 1; o < 64; o <<= 1) a += __shfl_xor(a, o);
    if (tid == 0) {
      float x = a + b2[0];
      out[b] = (x > 20.f) ? x : log1pf(__expf(x));
    }
  }
}

extern "C" void kernel_launch(void* const* d_in, const int* in_sizes, int n_in,
                              void* d_out, int out_size, void* d_ws, size_t ws_size,
                              hipStream_t stream) {
  const float* drug_k  = (const float*)d_in[0];
  const float* drug_v  = (const float*)d_in[1];
  const float* enz_k   = (const float*)d_in[2];
  const float* enz_v   = (const float*)d_in[3];
  const int*   drug_b  = (const int*)d_in[4];
  const int*   enz_b   = (const int*)d_in[5];
  const float* latents = (const float*)d_in[6];
  const float* wq_d    = (const float*)d_in[7];
  const float* bq_d    = (const float*)d_in[8];
  const float* wq_e    = (const float*)d_in[9];
  const float* bq_e    = (const float*)d_in[10];
  const float* mha_d_w = (const float*)d_in[11];
  const float* mha_d_b = (const float*)d_in[12];
  const float* mha_d_ow= (const float*)d_in[13];
  const float* mha_d_ob= (const float*)d_in[14];
  const float* mha_e_w = (const float*)d_in[15];
  const float* mha_e_b = (const float*)d_in[16];
  const float* mha_e_ow= (const float*)d_in[17];
  const float* mha_e_ob= (const float*)d_in[18];
  const float* ln1_g   = (const float*)d_in[19];
  const float* ln1_b   = (const float*)d_in[20];
  const float* ln2_g   = (const float*)d_in[21];
  const float* ln2_b   = (const float*)d_in[22];
  const float* ffn_w1  = (const float*)d_in[23];
  const float* ffn_b1  = (const float*)d_in[24];
  const float* ffn_w2  = (const float*)d_in[25];
  const float* ffn_b2  = (const float*)d_in[26];
  const float* head_w1 = (const float*)d_in[27];
  const float* head_b1 = (const float*)d_in[28];
  const float* head_w2 = (const float*)d_in[29];
  const float* head_b2 = (const float*)d_in[30];
  float* out = (float*)d_out;

  // ws layout
  int* seg = (int*)d_ws;                               // 2048 ints
  float* fws = (float*)d_ws;
  float* Wqf = fws + 2048;                             // 131072
  float* bqf = Wqf + 131072;                           // 1024
  float* lat = bqf + 1024;                             // 1048576
  float* l_d = lat + 1048576;                          // 32768
  float* l_e = l_d + 32768;                            // 65536
  unsigned short* Qt     = (unsigned short*)(l_e + 65536);  // 8388608 ush
  unsigned short* part_d = Qt + 8388608;                    // 4194304 ush
  unsigned short* part_e = part_d + 4194304;                // 8388608 ush  (~47 MB total)

  seg_kernel<<<2, 512, 0, stream>>>(drug_b, in_sizes[4], enz_b, in_sizes[5], seg);
  init_lat_kernel<<<4096, 256, 0, stream>>>(latents, lat);
  fold_kernel<<<8, 256, 0, stream>>>(wq_d, bq_d, wq_e, bq_e,
                                     mha_d_w, mha_d_b, mha_e_w, mha_e_b, Wqf, bqf);
  for (int l = 0; l < 4; ++l) {
    const float* mwd = mha_d_w + (size_t)l * 49152;
    const float* mbd = mha_d_b + l * 384;
    const float* mwe = mha_e_w + (size_t)l * 49152;
    const float* mbe = mha_e_b + l * 384;
    qtilde_kernel<<<512, 256, 0, stream>>>(lat, ln1_g + l * 128, ln1_b + l * 128,
        Wqf + (size_t)l * 32768, bqf + l * 256,
        mwd + 16384, mwe + 16384, Qt);
    attn2_kernel<<<512, 256, 0, stream>>>(drug_k, drug_v, seg, seg + 512,
        Qt, 16384, 128, 0, part_d, l_d);
    attn2_kernel<<<1024, 256, 0, stream>>>(enz_k, enz_v, seg + 1024, seg + 1536,
        Qt + 8192, 16384, 512, 1, part_e, l_e);
    post_kernel<<<512, 256, 0, stream>>>(part_d, l_d, part_e, l_e,
        mwd + 32768, mbd + 256, mha_d_ow + (size_t)l * 16384, mha_d_ob + l * 128,
        mwe + 32768, mbe + 256, mha_e_ow + (size_t)l * 16384, mha_e_ob + l * 128,
        ln2_g + l * 128, ln2_b + l * 128,
        ffn_w1 + (size_t)l * 32768, ffn_b1 + l * 256,
        ffn_w2 + (size_t)l * 32768, ffn_b2 + l * 128,
        lat);
  }
  head_kernel<<<512, 256, 0, stream>>>(lat, head_w1, head_b1, head_w2, head_b2, out);
}

// Round 3
// 1110.819 us; speedup vs baseline: 1.7888x; 1.1927x over previous
//
#include <hip/hip_runtime.h>
#include <math.h>

#define NBATCH 512
#define NL 16
#define DD 128
#define HH 4
#define HD 32

typedef __attribute__((ext_vector_type(8))) short short8;
typedef __attribute__((ext_vector_type(4))) float floatx4;

__device__ __forceinline__ unsigned short f2bf(float x) {
  union { float f; unsigned u; } v; v.f = x; return (unsigned short)(v.u >> 16);
}
__device__ __forceinline__ float bf2f(unsigned short s) {
  union { unsigned u; float f; } v; v.u = ((unsigned)s) << 16; return v.f;
}

// ---------------- segment table (batch arrays are sorted) ----------------
__global__ void seg_kernel(const int* __restrict__ db, int nd,
                           const int* __restrict__ eb, int ne,
                           int* __restrict__ seg) {
  const int* arr = (blockIdx.x == 0) ? db : eb;
  int n = (blockIdx.x == 0) ? nd : ne;
  int* start = seg + blockIdx.x * 1024;
  int* cnt = start + 512;
  int b = threadIdx.x;
  if (b < 512) {
    int lo = 0, hi = n;
    while (lo < hi) { int mid = (lo + hi) >> 1; if (arr[mid] < b) lo = mid + 1; else hi = mid; }
    int s = lo;
    lo = s; hi = n;
    while (lo < hi) { int mid = (lo + hi) >> 1; if (arr[mid] < b + 1) lo = mid + 1; else hi = mid; }
    start[b] = s; cnt[b] = lo - s;
  }
}

// ---------------- lat init (float4) ----------------
__global__ void init_lat_kernel(const float* __restrict__ latents, float* __restrict__ lat) {
  int i = blockIdx.x * blockDim.x + threadIdx.x;  // 262144 float4s
  ((float4*)lat)[i] = ((const float4*)latents)[i & 511];
}

// ---------------- fold: Wqf = mwq @ wq (scaled); 64 blocks, LDS-staged ----------------
__global__ __launch_bounds__(256) void fold_kernel(
    const float* __restrict__ wq_d, const float* __restrict__ bq_d,
    const float* __restrict__ wq_e, const float* __restrict__ bq_e,
    const float* __restrict__ mw_d, const float* __restrict__ mb_d,
    const float* __restrict__ mw_e, const float* __restrict__ mb_e,
    float* __restrict__ Wqf, float* __restrict__ bqf) {
  __shared__ __align__(16) float sMW[2048];
  const int pb = blockIdx.x >> 3, rg = blockIdx.x & 7;
  const int l = pb >> 1, p = pb & 1;
  const float* wq = (p == 0 ? wq_d : wq_e) + (size_t)l * 16384;
  const float* bq = (p == 0 ? bq_d : bq_e) + l * 128;
  const float* mw = (p == 0 ? mw_d : mw_e) + (size_t)l * 49152;
  const float* mb = (p == 0 ? mb_d : mb_e) + l * 384;
  const float scale = 0.17677669529663687f;  // 1/sqrt(32)
  const int tid = threadIdx.x;
  {
    const float4* src = (const float4*)(mw + rg * 2048);
    ((float4*)sMW)[tid] = src[tid];
    ((float4*)sMW)[tid + 256] = src[tid + 256];
  }
  __syncthreads();
  const int j = tid & 127, ih = tid >> 7;
  float acc[8];
#pragma unroll
  for (int r = 0; r < 8; ++r) acc[r] = 0.f;
#pragma unroll 4
  for (int k = 0; k < 128; ++k) {
    float wv = wq[k * 128 + j];
#pragma unroll
    for (int r = 0; r < 8; ++r) acc[r] += sMW[(ih * 8 + r) * 128 + k] * wv;
  }
  float* W = Wqf + (size_t)pb * 16384 + (rg * 16 + ih * 8) * 128 + j;
#pragma unroll
  for (int r = 0; r < 8; ++r) W[r * 128] = acc[r] * scale;
  if (rg == 0 && tid < 128) {
    float s = 0.f;
    const float* mr = mw + tid * 128;
    for (int k = 0; k < 128; ++k) s += mr[k] * bq[k];
    bqf[pb * 128 + tid] = (s + mb[tid]) * scale;
  }
}

// ---------------- per-layer Q~ precompute: LN1 + qh (both paths) + wk fold -> bf16 ----------------
__global__ __launch_bounds__(256) void qtilde_kernel(
    const float* __restrict__ lat,
    const float* __restrict__ lng, const float* __restrict__ lnb,
    const float* __restrict__ Wqf2, const float* __restrict__ bqf2,
    const float* __restrict__ wk_d, const float* __restrict__ wk_e,
    unsigned short* __restrict__ Qt) {
  __shared__ __align__(16) float sNL[2048];
  __shared__ __align__(16) float sQH[2][16 * 132];
  const int tid = threadIdx.x;
  const int b = blockIdx.x;
  // LN1
  {
    int q = tid >> 4, li = tid & 15, d0 = li * 8;
    const float* xr = lat + ((size_t)b * NL + q) * DD + d0;
    float x[8];
    *(float4*)(x) = *(const float4*)(xr);
    *(float4*)(x + 4) = *(const float4*)(xr + 4);
    float s1 = 0.f, s2 = 0.f;
#pragma unroll
    for (int j = 0; j < 8; ++j) { s1 += x[j]; s2 += x[j] * x[j]; }
#pragma unroll
    for (int o = 1; o < 16; o <<= 1) { s1 += __shfl_xor(s1, o); s2 += __shfl_xor(s2, o); }
    float mean = s1 * (1.f / 128.f);
    float var = s2 * (1.f / 128.f) - mean * mean;
    float rstd = rsqrtf(var + 1e-5f);
#pragma unroll
    for (int j = 0; j < 8; ++j)
      sNL[q * DD + d0 + j] = (x[j] - mean) * rstd * lng[d0 + j] + lnb[d0 + j];
  }
  __syncthreads();
  // qh[p][q][i] = nl @ Wqf^T + bqf
  {
    int p = tid >> 7, i = tid & 127;
    const float* wr = Wqf2 + p * 16384 + i * 128;
    float a[16];
#pragma unroll
    for (int q = 0; q < 16; ++q) a[q] = 0.f;
    for (int k4 = 0; k4 < 32; ++k4) {
      float4 w4 = *(const float4*)(wr + k4 * 4);
      int k = k4 * 4;
#pragma unroll
      for (int q = 0; q < 16; ++q)
        a[q] += w4.x * sNL[q * 128 + k] + w4.y * sNL[q * 128 + k + 1]
              + w4.z * sNL[q * 128 + k + 2] + w4.w * sNL[q * 128 + k + 3];
    }
    float bb = bqf2[p * 128 + i];
#pragma unroll
    for (int q = 0; q < 16; ++q) sQH[p][q * 132 + i] = a[q] + bb;
  }
  __syncthreads();
  // q~[(p,h,q)][d] = sum_j qh[p][q][h*32+j] * wk_p[h*32+j][d]  -> bf16
  {
    int rowp = tid >> 1, dh = tid & 1;
    int p = rowp >> 6, r = rowp & 63, h = r >> 4, q = r & 15;
    const float* wkp = (p == 0 ? wk_d : wk_e) + (h * 32) * 128;
    float qv[32];
#pragma unroll
    for (int j = 0; j < 32; ++j) qv[j] = sQH[p][q * 132 + h * 32 + j];
    unsigned short* outp = Qt + (((size_t)b * 2 + p) * 64 + r) * 128;
#pragma unroll
    for (int db = 0; db < 2; ++db) {
      int d0 = dh * 64 + db * 32;
      float acc[32];
#pragma unroll
      for (int d = 0; d < 32; ++d) acc[d] = 0.f;
      for (int j = 0; j < 32; ++j) {
        float qvj = qv[j];
        const float* wrow = wkp + j * 128 + d0;
#pragma unroll
        for (int d4 = 0; d4 < 8; ++d4) {
          float4 w4 = *(const float4*)(wrow + d4 * 4);
          acc[d4*4+0] += qvj * w4.x; acc[d4*4+1] += qvj * w4.y;
          acc[d4*4+2] += qvj * w4.z; acc[d4*4+3] += qvj * w4.w;
        }
      }
#pragma unroll
      for (int u = 0; u < 8; ++u) {
        ushort4 o4 = { f2bf(acc[u*4]), f2bf(acc[u*4+1]), f2bf(acc[u*4+2]), f2bf(acc[u*4+3]) };
        *(ushort4*)(outp + d0 + u * 4) = o4;
      }
    }
  }
}

// ---------------- fused MFMA flash attention, drug + enzyme in one dispatch ----------------
// blocks [0,1024): enzyme (split 2); blocks [1024,1536): drug.
__global__ __launch_bounds__(256, 4) void attn3_kernel(
    const float* __restrict__ Kd, const float* __restrict__ Vd,
    const float* __restrict__ Ke, const float* __restrict__ Ve,
    const int* __restrict__ seg,
    const unsigned short* __restrict__ Qt,
    unsigned short* __restrict__ part_d, float* __restrict__ l_d,
    unsigned short* __restrict__ part_e, float* __restrict__ l_e) {
  __shared__ __align__(16) unsigned short sK[32 * 136];  // row stride 272B
  __shared__ __align__(16) unsigned short sV[128 * 40];  // [dim][token], stride 80B
  __shared__ __align__(16) unsigned short sP[64 * 40];   // wave-private P
  const int tid = threadIdx.x;
  const int bi = blockIdx.x;

  const float* Kp; const float* Vp;
  const unsigned short* qt;
  unsigned short* part; float* lpart;
  int len, st;
  if (bi < 1024) {
    int b = bi >> 1, sp = bi & 1;
    int n = seg[1536 + b]; if (n > 512) n = 512;
    int chunk = (n + 1) >> 1;
    int begin = sp * chunk;
    len = n - begin; if (len > chunk) len = chunk; if (len < 0) len = 0;
    st = seg[1024 + b] + begin;
    Kp = Ke; Vp = Ve;
    qt = Qt + ((size_t)b * 2 + 1) * 8192;
    part = part_e + (size_t)bi * 8192;   // bi == b*2+sp
    lpart = l_e + (size_t)bi * 64;
  } else {
    int b = bi - 1024;
    int n = seg[512 + b]; if (n > 128) n = 128;
    len = n;
    st = seg[b];
    Kp = Kd; Vp = Vd;
    qt = Qt + (size_t)b * 2 * 8192;
    part = part_d + (size_t)b * 8192;
    lpart = l_d + (size_t)b * 64;
  }

  const int lane = tid & 63;
  const int w = tid >> 6;
  const int m = lane & 15;
  const int quad = lane >> 4;

  // A-frags: q~ rows of this wave (A[m][k=c*32+quad*8+j])
  short8 qA[4];
  {
    const unsigned short* qrow = qt + (size_t)(w * 16 + m) * 128 + quad * 8;
#pragma unroll
    for (int c = 0; c < 4; ++c) qA[c] = *(const short8*)(qrow + c * 32);
  }

  floatx4 oA[8];
#pragma unroll
  for (int i = 0; i < 8; ++i) oA[i] = (floatx4){0.f, 0.f, 0.f, 0.f};
  float lp[4] = {0.f, 0.f, 0.f, 0.f};

  float4 rK[4], rV[4];
  auto load_tile = [&](int t0) {
    int nv = len - t0; if (nv > 32) nv = 32;
#pragma unroll
    for (int it = 0; it < 4; ++it) {
      int f = tid + it * 256;
      int tok = f >> 5, seg_ = f & 31;
      rK[it] = (tok < nv) ? *(const float4*)(Kp + (size_t)(st + t0 + tok) * 128 + seg_ * 4)
                          : (float4){0.f, 0.f, 0.f, 0.f};
    }
#pragma unroll
    for (int it = 0; it < 4; ++it) {
      int f = tid + it * 256;
      int tok = f & 31, seg_ = f >> 5;
      rV[it] = (tok < nv) ? *(const float4*)(Vp + (size_t)(st + t0 + tok) * 128 + seg_ * 4)
                          : (float4){0.f, 0.f, 0.f, 0.f};
    }
  };
  auto store_tile = [&]() {
#pragma unroll
    for (int it = 0; it < 4; ++it) {
      int f = tid + it * 256;
      int tok = f >> 5, seg_ = f & 31;
      ushort4 u = { f2bf(rK[it].x), f2bf(rK[it].y), f2bf(rK[it].z), f2bf(rK[it].w) };
      *(ushort4*)(sK + tok * 136 + seg_ * 4) = u;
    }
#pragma unroll
    for (int it = 0; it < 4; ++it) {
      int f = tid + it * 256;
      int tok = f & 31, seg_ = f >> 5;
      int d0 = seg_ * 4;
      sV[(d0 + 0) * 40 + tok] = f2bf(rV[it].x);
      sV[(d0 + 1) * 40 + tok] = f2bf(rV[it].y);
      sV[(d0 + 2) * 40 + tok] = f2bf(rV[it].z);
      sV[(d0 + 3) * 40 + tok] = f2bf(rV[it].w);
    }
  };

  if (len > 0) load_tile(0);
  for (int t0 = 0; t0 < len; t0 += 32) {
    __syncthreads();
    store_tile();
    __syncthreads();
    if (t0 + 32 < len) load_tile(t0 + 32);
    int nv = len - t0; if (nv > 32) nv = 32;
    // S = Q~ @ K^T
    floatx4 sS[2];
    sS[0] = (floatx4){0.f, 0.f, 0.f, 0.f};
    sS[1] = (floatx4){0.f, 0.f, 0.f, 0.f};
#pragma unroll
    for (int g = 0; g < 2; ++g)
#pragma unroll
      for (int c = 0; c < 4; ++c) {
        short8 kB = *(const short8*)(sK + (g * 16 + m) * 136 + c * 32 + quad * 8);
        sS[g] = __builtin_amdgcn_mfma_f32_16x16x32_bf16(qA[c], kB, sS[g], 0, 0, 0);
      }
    // P = exp(S)  (no max-shift: |s| << 1 by construction), mask tail, accumulate l
#pragma unroll
    for (int g = 0; g < 2; ++g) {
      bool valid = (g * 16 + m) < nv;
#pragma unroll
      for (int r = 0; r < 4; ++r) {
        float p = valid ? __expf(sS[g][r]) : 0.f;
        lp[r] += p;
        sP[(w * 16 + quad * 4 + r) * 40 + g * 16 + m] = f2bf(p);
      }
    }
    // PV: o += P @ V
    short8 pA = *(const short8*)(sP + (w * 16 + m) * 40 + quad * 8);
#pragma unroll
    for (int dg = 0; dg < 8; ++dg) {
      short8 vB = *(const short8*)(sV + (dg * 16 + m) * 40 + quad * 8);
      oA[dg] = __builtin_amdgcn_mfma_f32_16x16x32_bf16(pA, vB, oA[dg], 0, 0, 0);
    }
  }

  // reduce l across the 16 token-columns
#pragma unroll
  for (int r = 0; r < 4; ++r) {
    float v = lp[r];
    v += __shfl_xor(v, 1); v += __shfl_xor(v, 2);
    v += __shfl_xor(v, 4); v += __shfl_xor(v, 8);
    lp[r] = v;
  }
  if (m == 0) {
#pragma unroll
    for (int r = 0; r < 4; ++r)
      lpart[w * 16 + quad * 4 + r] = lp[r];
  }
#pragma unroll
  for (int dg = 0; dg < 8; ++dg)
#pragma unroll
    for (int r = 0; r < 4; ++r)
      part[(w * 16 + quad * 4 + r) * 128 + dg * 16 + m] = f2bf(oA[dg][r]);
}

// ---------------- combine partials + wv/ow + residual + LN2 + FFN ----------------
__global__ __launch_bounds__(256) void post_kernel(
    const unsigned short* __restrict__ pd, const float* __restrict__ ldv,
    const unsigned short* __restrict__ pe, const float* __restrict__ lev,
    const float* __restrict__ wv_d, const float* __restrict__ bv_d,
    const float* __restrict__ ow_d, const float* __restrict__ ob_d,
    const float* __restrict__ wv_e, const float* __restrict__ bv_e,
    const float* __restrict__ ow_e, const float* __restrict__ ob_e,
    const float* __restrict__ ln2g, const float* __restrict__ ln2b,
    const float* __restrict__ w1, const float* __restrict__ b1,
    const float* __restrict__ w2, const float* __restrict__ b2,
    float* __restrict__ lat) {
  __shared__ __align__(16) float sO[8192];
  __shared__ __align__(16) float sVH[2048];
  __shared__ __align__(16) float sAcc[2048];
  __shared__ float sLd[64], sLe[64];
  const int tid = threadIdx.x;
  const int b = blockIdx.x;

  if (tid < 64) {
    float v = ldv[(size_t)b * 64 + tid];
    sLd[tid] = (v > 0.f) ? 1.f / v : 0.f;
  } else if (tid < 128) {
    int r = tid - 64;
    float v = lev[((size_t)b * 2) * 64 + r] + lev[((size_t)b * 2 + 1) * 64 + r];
    sLe[r] = (v > 0.f) ? 1.f / v : 0.f;
  }
  __syncthreads();
  // S1: drug o normalized -> sO
  {
    const unsigned short* src = pd + (size_t)b * 8192;
#pragma unroll
    for (int it = 0; it < 8; ++it) {
      int idx = tid + it * 256;
      ushort4 u = *(const ushort4*)(src + idx * 4);
      float sc = sLd[idx >> 5];
      sO[idx * 4 + 0] = bf2f(u.x) * sc;
      sO[idx * 4 + 1] = bf2f(u.y) * sc;
      sO[idx * 4 + 2] = bf2f(u.z) * sc;
      sO[idx * 4 + 3] = bf2f(u.w) * sc;
    }
  }
  __syncthreads();
  // S2: vh_d
  {
    int i = tid >> 1, kh = tid & 1, hh = i >> 5;
    float a[16];
#pragma unroll
    for (int q = 0; q < 16; ++q) a[q] = 0.f;
    const float* wr = wv_d + i * 128 + kh * 64;
    const float* xb = sO + (hh * 16) * 128 + kh * 64;
    for (int k4 = 0; k4 < 16; ++k4) {
      float4 w4 = *(const float4*)(wr + k4 * 4);
      int kk = k4 * 4;
#pragma unroll
      for (int q = 0; q < 16; ++q)
        a[q] += w4.x * xb[q*128+kk] + w4.y * xb[q*128+kk+1]
              + w4.z * xb[q*128+kk+2] + w4.w * xb[q*128+kk+3];
    }
#pragma unroll
    for (int q = 0; q < 16; ++q) a[q] += __shfl_xor(a[q], 1);
    float bb = bv_d[i];
#pragma unroll
    for (int q8 = 0; q8 < 8; ++q8) { int q = kh * 8 + q8; sVH[q * 128 + i] = a[q] + bb; }
  }
  __syncthreads();
  // S3: acc = lat + ow_d·vh_d + ob_d ; then stage combined enzyme o into sO
  {
    int i = tid >> 1, kh = tid & 1;
    float a[16];
#pragma unroll
    for (int q = 0; q < 16; ++q) a[q] = 0.f;
    const float* wr = ow_d + i * 128 + kh * 64;
    const float* xb = sVH + kh * 64;
    for (int k4 = 0; k4 < 16; ++k4) {
      float4 w4 = *(const float4*)(wr + k4 * 4);
      int kk = k4 * 4;
#pragma unroll
      for (int q = 0; q < 16; ++q)
        a[q] += w4.x * xb[q*128+kk] + w4.y * xb[q*128+kk+1]
              + w4.z * xb[q*128+kk+2] + w4.w * xb[q*128+kk+3];
    }
#pragma unroll
    for (int q = 0; q < 16; ++q) a[q] += __shfl_xor(a[q], 1);
    float bb = ob_d[i];
#pragma unroll
    for (int q8 = 0; q8 < 8; ++q8) {
      int q = kh * 8 + q8;
      sAcc[q * 128 + i] = lat[((size_t)b * 16 + q) * 128 + i] + a[q] + bb;
    }
  }
  {
    const unsigned short* s0 = pe + (size_t)(b * 2) * 8192;
    const unsigned short* s1 = pe + (size_t)(b * 2 + 1) * 8192;
#pragma unroll
    for (int it = 0; it < 8; ++it) {
      int idx = tid + it * 256;
      ushort4 u0 = *(const ushort4*)(s0 + idx * 4);
      ushort4 u1 = *(const ushort4*)(s1 + idx * 4);
      float sc = sLe[idx >> 5];
      sO[idx * 4 + 0] = (bf2f(u0.x) + bf2f(u1.x)) * sc;
      sO[idx * 4 + 1] = (bf2f(u0.y) + bf2f(u1.y)) * sc;
      sO[idx * 4 + 2] = (bf2f(u0.z) + bf2f(u1.z)) * sc;
      sO[idx * 4 + 3] = (bf2f(u0.w) + bf2f(u1.w)) * sc;
    }
  }
  __syncthreads();
  // S5: vh_e
  {
    int i = tid >> 1, kh = tid & 1, hh = i >> 5;
    float a[16];
#pragma unroll
    for (int q = 0; q < 16; ++q) a[q] = 0.f;
    const float* wr = wv_e + i * 128 + kh * 64;
    const float* xb = sO + (hh * 16) * 128 + kh * 64;
    for (int k4 = 0; k4 < 16; ++k4) {
      float4 w4 = *(const float4*)(wr + k4 * 4);
      int kk = k4 * 4;
#pragma unroll
      for (int q = 0; q < 16; ++q)
        a[q] += w4.x * xb[q*128+kk] + w4.y * xb[q*128+kk+1]
              + w4.z * xb[q*128+kk+2] + w4.w * xb[q*128+kk+3];
    }
#pragma unroll
    for (int q = 0; q < 16; ++q) a[q] += __shfl_xor(a[q], 1);
    float bb = bv_e[i];
#pragma unroll
    for (int q8 = 0; q8 < 8; ++q8) { int q = kh * 8 + q8; sVH[q * 128 + i] = a[q] + bb; }
  }
  __syncthreads();
  // S6: acc += ow_e·vh_e + ob_e
  {
    int i = tid >> 1, kh = tid & 1;
    float a[16];
#pragma unroll
    for (int q = 0; q < 16; ++q) a[q] = 0.f;
    const float* wr = ow_e + i * 128 + kh * 64;
    const float* xb = sVH + kh * 64;
    for (int k4 = 0; k4 < 16; ++k4) {
      float4 w4 = *(const float4*)(wr + k4 * 4);
      int kk = k4 * 4;
#pragma unroll
      for (int q = 0; q < 16; ++q)
        a[q] += w4.x * xb[q*128+kk] + w4.y * xb[q*128+kk+1]
              + w4.z * xb[q*128+kk+2] + w4.w * xb[q*128+kk+3];
    }
#pragma unroll
    for (int q = 0; q < 16; ++q) a[q] += __shfl_xor(a[q], 1);
    float bb = ob_e[i];
#pragma unroll
    for (int q8 = 0; q8 < 8; ++q8) { int q = kh * 8 + q8; sAcc[q * 128 + i] += a[q] + bb; }
  }
  __syncthreads();
  // S7: LN2 -> sO[0..2047]
  {
    int q = tid >> 4, li = tid & 15, d0 = li * 8;
    float x[8];
#pragma unroll
    for (int j = 0; j < 8; ++j) x[j] = sAcc[q * 128 + d0 + j];
    float s1 = 0.f, s2 = 0.f;
#pragma unroll
    for (int j = 0; j < 8; ++j) { s1 += x[j]; s2 += x[j] * x[j]; }
#pragma unroll
    for (int o = 1; o < 16; o <<= 1) { s1 += __shfl_xor(s1, o); s2 += __shfl_xor(s2, o); }
    float mean = s1 * (1.f / 128.f);
    float var = s2 * (1.f / 128.f) - mean * mean;
    float rstd = rsqrtf(var + 1e-5f);
#pragma unroll
    for (int j = 0; j < 8; ++j)
      sO[q * 128 + d0 + j] = (x[j] - mean) * rstd * ln2g[d0 + j] + ln2b[d0 + j];
  }
  __syncthreads();
  // S8: f1 = relu(h1 @ w1^T + b1)
  {
    int o = tid;
    float a[16];
#pragma unroll
    for (int q = 0; q < 16; ++q) a[q] = 0.f;
    const float* wr = w1 + o * 128;
    for (int k4 = 0; k4 < 32; ++k4) {
      float4 w4 = *(const float4*)(wr + k4 * 4);
      int k = k4 * 4;
#pragma unroll
      for (int q = 0; q < 16; ++q)
        a[q] += w4.x * sO[q*128+k] + w4.y * sO[q*128+k+1]
              + w4.z * sO[q*128+k+2] + w4.w * sO[q*128+k+3];
    }
    float bb = b1[o];
#pragma unroll
    for (int q = 0; q < 16; ++q) sO[2048 + q * 256 + o] = fmaxf(a[q] + bb, 0.f);
  }
  __syncthreads();
  // S9: lat = acc + f1 @ w2^T + b2
  {
    int i = tid >> 1, kh = tid & 1;
    float a[16];
#pragma unroll
    for (int q = 0; q < 16; ++q) a[q] = 0.f;
    const float* wr = w2 + i * 256 + kh * 128;
    const float* xb = sO + 2048 + kh * 128;
    for (int k4 = 0; k4 < 32; ++k4) {
      float4 w4 = *(const float4*)(wr + k4 * 4);
      int kk = k4 * 4;
#pragma unroll
      for (int q = 0; q < 16; ++q)
        a[q] += w4.x * xb[q*256+kk] + w4.y * xb[q*256+kk+1]
              + w4.z * xb[q*256+kk+2] + w4.w * xb[q*256+kk+3];
    }
#pragma unroll
    for (int q = 0; q < 16; ++q) a[q] += __shfl_xor(a[q], 1);
    float bb = b2[i];
#pragma unroll
    for (int q8 = 0; q8 < 8; ++q8) {
      int q = kh * 8 + q8;
      lat[((size_t)b * 16 + q) * 128 + i] = sAcc[q * 128 + i] + a[q] + bb;
    }
  }
}

// ---------------- head ----------------
__global__ __launch_bounds__(256) void head_kernel(const float* __restrict__ lat,
                                                   const float* __restrict__ w1,
                                                   const float* __restrict__ b1,
                                                   const float* __restrict__ w2,
                                                   const float* __restrict__ b2,
                                                   float* __restrict__ out) {
  __shared__ __align__(16) float sX[2048];
  __shared__ float sH[128];
  const int tid = threadIdx.x;
  const int b = blockIdx.x;
  {
    const float4* src = (const float4*)(lat + (size_t)b * 2048);
#pragma unroll
    for (int it = 0; it < 2; ++it) ((float4*)sX)[tid + it * 256] = src[tid + it * 256];
  }
  __syncthreads();
  {
    int o = tid >> 1, kh = tid & 1;
    float a = 0.f;
    const float* wr = w1 + (size_t)o * 2048 + kh * 1024;
    const float* xb = sX + kh * 1024;
    for (int k4 = 0; k4 < 256; ++k4) {
      float4 w4 = *(const float4*)(wr + k4 * 4);
      float4 x4 = *(const float4*)(xb + k4 * 4);
      a += w4.x * x4.x + w4.y * x4.y + w4.z * x4.z + w4.w * x4.w;
    }
    a += __shfl_xor(a, 1);
    if (kh == 0) sH[o] = fmaxf(a + b1[o], 0.f);
  }
  __syncthreads();
  if (tid < 64) {
    float a = sH[tid] * w2[tid] + sH[tid + 64] * w2[tid + 64];
#pragma unroll
    for (int o = 1; o < 64; o <<= 1) a += __shfl_xor(a, o);
    if (tid == 0) {
      float x = a + b2[0];
      out[b] = (x > 20.f) ? x : log1pf(__expf(x));
    }
  }
}

extern "C" void kernel_launch(void* const* d_in, const int* in_sizes, int n_in,
                              void* d_out, int out_size, void* d_ws, size_t ws_size,
                              hipStream_t stream) {
  const float* drug_k  = (const float*)d_in[0];
  const float* drug_v  = (const float*)d_in[1];
  const float* enz_k   = (const float*)d_in[2];
  const float* enz_v   = (const float*)d_in[3];
  const int*   drug_b  = (const int*)d_in[4];
  const int*   enz_b   = (const int*)d_in[5];
  const float* latents = (const float*)d_in[6];
  const float* wq_d    = (const float*)d_in[7];
  const float* bq_d    = (const float*)d_in[8];
  const float* wq_e    = (const float*)d_in[9];
  const float* bq_e    = (const float*)d_in[10];
  const float* mha_d_w = (const float*)d_in[11];
  const float* mha_d_b = (const float*)d_in[12];
  const float* mha_d_ow= (const float*)d_in[13];
  const float* mha_d_ob= (const float*)d_in[14];
  const float* mha_e_w = (const float*)d_in[15];
  const float* mha_e_b = (const float*)d_in[16];
  const float* mha_e_ow= (const float*)d_in[17];
  const float* mha_e_ob= (const float*)d_in[18];
  const float* ln1_g   = (const float*)d_in[19];
  const float* ln1_b   = (const float*)d_in[20];
  const float* ln2_g   = (const float*)d_in[21];
  const float* ln2_b   = (const float*)d_in[22];
  const float* ffn_w1  = (const float*)d_in[23];
  const float* ffn_b1  = (const float*)d_in[24];
  const float* ffn_w2  = (const float*)d_in[25];
  const float* ffn_b2  = (const float*)d_in[26];
  const float* head_w1 = (const float*)d_in[27];
  const float* head_b1 = (const float*)d_in[28];
  const float* head_w2 = (const float*)d_in[29];
  const float* head_b2 = (const float*)d_in[30];
  float* out = (float*)d_out;

  // ws layout
  int* seg = (int*)d_ws;                               // 2048 ints
  float* fws = (float*)d_ws;
  float* Wqf = fws + 2048;                             // 131072
  float* bqf = Wqf + 131072;                           // 1024
  float* lat = bqf + 1024;                             // 1048576
  float* l_d = lat + 1048576;                          // 32768
  float* l_e = l_d + 32768;                            // 65536
  unsigned short* Qt     = (unsigned short*)(l_e + 65536);  // 8388608 ush
  unsigned short* part_d = Qt + 8388608;                    // 4194304 ush
  unsigned short* part_e = part_d + 4194304;                // 8388608 ush  (~47 MB total)

  seg_kernel<<<2, 512, 0, stream>>>(drug_b, in_sizes[4], enz_b, in_sizes[5], seg);
  init_lat_kernel<<<1024, 256, 0, stream>>>(latents, lat);
  fold_kernel<<<64, 256, 0, stream>>>(wq_d, bq_d, wq_e, bq_e,
                                      mha_d_w, mha_d_b, mha_e_w, mha_e_b, Wqf, bqf);
  for (int l = 0; l < 4; ++l) {
    const float* mwd = mha_d_w + (size_t)l * 49152;
    const float* mbd = mha_d_b + l * 384;
    const float* mwe = mha_e_w + (size_t)l * 49152;
    const float* mbe = mha_e_b + l * 384;
    qtilde_kernel<<<512, 256, 0, stream>>>(lat, ln1_g + l * 128, ln1_b + l * 128,
        Wqf + (size_t)l * 32768, bqf + l * 256,
        mwd + 16384, mwe + 16384, Qt);
    attn3_kernel<<<1536, 256, 0, stream>>>(drug_k, drug_v, enz_k, enz_v, seg,
        Qt, part_d, l_d, part_e, l_e);
    post_kernel<<<512, 256, 0, stream>>>(part_d, l_d, part_e, l_e,
        mwd + 32768, mbd + 256, mha_d_ow + (size_t)l * 16384, mha_d_ob + l * 128,
        mwe + 32768, mbe + 256, mha_e_ow + (size_t)l * 16384, mha_e_ob + l * 128,
        ln2_g + l * 128, ln2_b + l * 128,
        ffn_w1 + (size_t)l * 32768, ffn_b1 + l * 256,
        ffn_w2 + (size_t)l * 32768, ffn_b2 + l * 128,
        lat);
  }
  head_kernel<<<512, 256, 0, stream>>>(lat, head_w1, head_b1, head_w2, head_b2, out);
}

// Round 4
// 881.199 us; speedup vs baseline: 2.2549x; 1.2606x over previous
//
#include <hip/hip_runtime.h>
#include <math.h>

#define NL 16
#define DD 128

typedef __attribute__((ext_vector_type(8))) short short8;
typedef __attribute__((ext_vector_type(4))) float floatx4;

union U8 { short8 v; unsigned short s[8]; };

__device__ __forceinline__ unsigned short f2bf(float x) {
  union { float f; unsigned u; } v; v.f = x; return (unsigned short)(v.u >> 16);
}
__device__ __forceinline__ float bf2f(unsigned short s) {
  union { unsigned u; float f; } v; v.u = ((unsigned)s) << 16; return v.f;
}

// ---------------- segment table ----------------
__global__ void seg_kernel(const int* __restrict__ db, int nd,
                           const int* __restrict__ eb, int ne,
                           int* __restrict__ seg) {
  const int* arr = (blockIdx.x == 0) ? db : eb;
  int n = (blockIdx.x == 0) ? nd : ne;
  int* start = seg + blockIdx.x * 1024;
  int* cnt = start + 512;
  int b = threadIdx.x;
  if (b < 512) {
    int lo = 0, hi = n;
    while (lo < hi) { int mid = (lo + hi) >> 1; if (arr[mid] < b) lo = mid + 1; else hi = mid; }
    int s = lo;
    lo = s; hi = n;
    while (lo < hi) { int mid = (lo + hi) >> 1; if (arr[mid] < b + 1) lo = mid + 1; else hi = mid; }
    start[b] = s; cnt[b] = lo - s;
  }
}

// ---------------- lat init (float4) ----------------
__global__ void init_lat_kernel(const float* __restrict__ latents, float* __restrict__ lat) {
  int i = blockIdx.x * blockDim.x + threadIdx.x;
  ((float4*)lat)[i] = ((const float4*)latents)[i & 511];
}

// ---------------- fp32 -> bf16 convert ----------------
__global__ void cvt_kernel(const float* __restrict__ src, unsigned short* __restrict__ dst, int n4) {
  int i = blockIdx.x * blockDim.x + threadIdx.x;
  if (i < n4) {
    float4 v = ((const float4*)src)[i];
    ushort4 o = { f2bf(v.x), f2bf(v.y), f2bf(v.z), f2bf(v.w) };
    ((ushort4*)dst)[i] = o;
  }
}

// convert post weights to bf16, per-layer contiguous blocks
__global__ void cvtw_kernel(const float* __restrict__ mw_d, const float* __restrict__ ow_d,
                            const float* __restrict__ mw_e, const float* __restrict__ ow_e,
                            const float* __restrict__ w1, const float* __restrict__ w2,
                            unsigned short* __restrict__ Wbf) {
  int l = blockIdx.x >> 7, blk = blockIdx.x & 127;
  int idx = blk * 1024 + threadIdx.x * 4;
  const float* src; int off;
  if (idx < 16384)      { src = mw_d + (size_t)l * 49152 + 32768; off = idx; }
  else if (idx < 32768) { src = ow_d + (size_t)l * 16384; off = idx - 16384; }
  else if (idx < 49152) { src = mw_e + (size_t)l * 49152 + 32768; off = idx - 32768; }
  else if (idx < 65536) { src = ow_e + (size_t)l * 16384; off = idx - 49152; }
  else if (idx < 98304) { src = w1 + (size_t)l * 32768; off = idx - 65536; }
  else                  { src = w2 + (size_t)l * 32768; off = idx - 98304; }
  float4 v = *(const float4*)(src + off);
  ushort4 o = { f2bf(v.x), f2bf(v.y), f2bf(v.z), f2bf(v.w) };
  *(ushort4*)(Wbf + (size_t)l * 131072 + idx) = o;
}

// ---------------- fold: Wqf = mwq @ wq (scaled) ----------------
__global__ __launch_bounds__(256) void fold_kernel(
    const float* __restrict__ wq_d, const float* __restrict__ bq_d,
    const float* __restrict__ wq_e, const float* __restrict__ bq_e,
    const float* __restrict__ mw_d, const float* __restrict__ mb_d,
    const float* __restrict__ mw_e, const float* __restrict__ mb_e,
    float* __restrict__ Wqf, float* __restrict__ bqf) {
  __shared__ __align__(16) float sMW[2048];
  const int pb = blockIdx.x >> 3, rg = blockIdx.x & 7;
  const int l = pb >> 1, p = pb & 1;
  const float* wq = (p == 0 ? wq_d : wq_e) + (size_t)l * 16384;
  const float* bq = (p == 0 ? bq_d : bq_e) + l * 128;
  const float* mw = (p == 0 ? mw_d : mw_e) + (size_t)l * 49152;
  const float* mb = (p == 0 ? mb_d : mb_e) + l * 384;
  const float scale = 0.17677669529663687f;
  const int tid = threadIdx.x;
  {
    const float4* src = (const float4*)(mw + rg * 2048);
    ((float4*)sMW)[tid] = src[tid];
    ((float4*)sMW)[tid + 256] = src[tid + 256];
  }
  __syncthreads();
  const int j = tid & 127, ih = tid >> 7;
  float acc[8];
#pragma unroll
  for (int r = 0; r < 8; ++r) acc[r] = 0.f;
#pragma unroll 4
  for (int k = 0; k < 128; ++k) {
    float wv = wq[k * 128 + j];
#pragma unroll
    for (int r = 0; r < 8; ++r) acc[r] += sMW[(ih * 8 + r) * 128 + k] * wv;
  }
  float* W = Wqf + (size_t)pb * 16384 + (rg * 16 + ih * 8) * 128 + j;
#pragma unroll
  for (int r = 0; r < 8; ++r) W[r * 128] = acc[r] * scale;
  if (rg == 0 && tid < 128) {
    float s = 0.f;
    const float* mr = mw + tid * 128;
    for (int k = 0; k < 128; ++k) s += mr[k] * bq[k];
    bqf[pb * 128 + tid] = (s + mb[tid]) * scale;
  }
}

// ---------------- per-layer Q~: LN1 + qh + wk fold -> bf16 ----------------
__global__ __launch_bounds__(256) void qtilde_kernel(
    const float* __restrict__ lat,
    const float* __restrict__ lng, const float* __restrict__ lnb,
    const float* __restrict__ Wqf2, const float* __restrict__ bqf2,
    const float* __restrict__ wk_d, const float* __restrict__ wk_e,
    unsigned short* __restrict__ Qt) {
  __shared__ __align__(16) float sNL[2048];
  __shared__ __align__(16) float sQH[2][16 * 132];
  const int tid = threadIdx.x;
  const int b = blockIdx.x;
  {
    int q = tid >> 4, li = tid & 15, d0 = li * 8;
    const float* xr = lat + ((size_t)b * NL + q) * DD + d0;
    float x[8];
    *(float4*)(x) = *(const float4*)(xr);
    *(float4*)(x + 4) = *(const float4*)(xr + 4);
    float s1 = 0.f, s2 = 0.f;
#pragma unroll
    for (int j = 0; j < 8; ++j) { s1 += x[j]; s2 += x[j] * x[j]; }
#pragma unroll
    for (int o = 1; o < 16; o <<= 1) { s1 += __shfl_xor(s1, o); s2 += __shfl_xor(s2, o); }
    float mean = s1 * (1.f / 128.f);
    float var = s2 * (1.f / 128.f) - mean * mean;
    float rstd = rsqrtf(var + 1e-5f);
#pragma unroll
    for (int j = 0; j < 8; ++j)
      sNL[q * DD + d0 + j] = (x[j] - mean) * rstd * lng[d0 + j] + lnb[d0 + j];
  }
  __syncthreads();
  {
    int p = tid >> 7, i = tid & 127;
    const float* wr = Wqf2 + p * 16384 + i * 128;
    float a[16];
#pragma unroll
    for (int q = 0; q < 16; ++q) a[q] = 0.f;
    for (int k4 = 0; k4 < 32; ++k4) {
      float4 w4 = *(const float4*)(wr + k4 * 4);
      int k = k4 * 4;
#pragma unroll
      for (int q = 0; q < 16; ++q)
        a[q] += w4.x * sNL[q * 128 + k] + w4.y * sNL[q * 128 + k + 1]
              + w4.z * sNL[q * 128 + k + 2] + w4.w * sNL[q * 128 + k + 3];
    }
    float bb = bqf2[p * 128 + i];
#pragma unroll
    for (int q = 0; q < 16; ++q) sQH[p][q * 132 + i] = a[q] + bb;
  }
  __syncthreads();
  {
    int rowp = tid >> 1, dh = tid & 1;
    int p = rowp >> 6, r = rowp & 63, h = r >> 4, q = r & 15;
    const float* wkp = (p == 0 ? wk_d : wk_e) + (h * 32) * 128;
    float qv[32];
#pragma unroll
    for (int j = 0; j < 32; ++j) qv[j] = sQH[p][q * 132 + h * 32 + j];
    unsigned short* outp = Qt + (((size_t)b * 2 + p) * 64 + r) * 128;
#pragma unroll
    for (int db = 0; db < 2; ++db) {
      int d0 = dh * 64 + db * 32;
      float acc[32];
#pragma unroll
      for (int d = 0; d < 32; ++d) acc[d] = 0.f;
      for (int j = 0; j < 32; ++j) {
        float qvj = qv[j];
        const float* wrow = wkp + j * 128 + d0;
#pragma unroll
        for (int d4 = 0; d4 < 8; ++d4) {
          float4 w4 = *(const float4*)(wrow + d4 * 4);
          acc[d4*4+0] += qvj * w4.x; acc[d4*4+1] += qvj * w4.y;
          acc[d4*4+2] += qvj * w4.z; acc[d4*4+3] += qvj * w4.w;
        }
      }
#pragma unroll
      for (int u = 0; u < 8; ++u) {
        ushort4 o4 = { f2bf(acc[u*4]), f2bf(acc[u*4+1]), f2bf(acc[u*4+2]), f2bf(acc[u*4+3]) };
        *(ushort4*)(outp + d0 + u * 4) = o4;
      }
    }
  }
}

// ---------------- fused MFMA flash attention (bf16 K/V), drug + enzyme(x4 split) ----------------
__global__ __launch_bounds__(256, 4) void attn3_kernel(
    const unsigned short* __restrict__ Kd, const unsigned short* __restrict__ Vd,
    const unsigned short* __restrict__ Ke, const unsigned short* __restrict__ Ve,
    const int* __restrict__ seg,
    const unsigned short* __restrict__ Qt,
    unsigned short* __restrict__ part_d, float* __restrict__ l_d,
    unsigned short* __restrict__ part_e, float* __restrict__ l_e) {
  __shared__ __align__(16) unsigned short sK[32 * 136];
  __shared__ __align__(16) unsigned short sV[128 * 40];
  __shared__ __align__(16) unsigned short sP[64 * 40];
  const int tid = threadIdx.x;
  const int bi = blockIdx.x;

  const unsigned short* Kp; const unsigned short* Vp;
  const unsigned short* qt;
  unsigned short* part; float* lpart;
  int len, st;
  if (bi < 2048) {
    int b = bi >> 2, sp = bi & 3;
    int n = seg[1536 + b]; if (n > 512) n = 512;
    int chunk = (n + 3) >> 2;
    int begin = sp * chunk;
    len = n - begin; if (len > chunk) len = chunk; if (len < 0) len = 0;
    st = seg[1024 + b] + begin;
    Kp = Ke; Vp = Ve;
    qt = Qt + ((size_t)b * 2 + 1) * 8192;
    part = part_e + (size_t)bi * 8192;
    lpart = l_e + (size_t)bi * 64;
  } else {
    int b = bi - 2048;
    int n = seg[512 + b]; if (n > 128) n = 128;
    len = n;
    st = seg[b];
    Kp = Kd; Vp = Vd;
    qt = Qt + (size_t)b * 2 * 8192;
    part = part_d + (size_t)b * 8192;
    lpart = l_d + (size_t)b * 64;
  }

  const int lane = tid & 63;
  const int w = tid >> 6;
  const int m = lane & 15;
  const int quad = lane >> 4;

  short8 qA[4];
  {
    const unsigned short* qrow = qt + (size_t)(w * 16 + m) * 128 + quad * 8;
#pragma unroll
    for (int c = 0; c < 4; ++c) qA[c] = *(const short8*)(qrow + c * 32);
  }

  floatx4 oA[8];
#pragma unroll
  for (int i = 0; i < 8; ++i) oA[i] = (floatx4){0.f, 0.f, 0.f, 0.f};
  float lp[4] = {0.f, 0.f, 0.f, 0.f};

  short8 rK[2], rV[2];
  const short8 z8 = {0, 0, 0, 0, 0, 0, 0, 0};
  auto load_tile = [&](int t0) {
    int nv = len - t0; if (nv > 32) nv = 32;
#pragma unroll
    for (int it = 0; it < 2; ++it) {
      int f = tid + it * 256;
      int tok = f >> 4, d8 = f & 15;
      rK[it] = (tok < nv) ? *(const short8*)(Kp + (size_t)(st + t0 + tok) * 128 + d8 * 8) : z8;
    }
#pragma unroll
    for (int it = 0; it < 2; ++it) {
      int f = tid + it * 256;
      int tok = f & 31, d8 = f >> 5;
      rV[it] = (tok < nv) ? *(const short8*)(Vp + (size_t)(st + t0 + tok) * 128 + d8 * 8) : z8;
    }
  };
  auto store_tile = [&]() {
#pragma unroll
    for (int it = 0; it < 2; ++it) {
      int f = tid + it * 256;
      int tok = f >> 4, d8 = f & 15;
      *(short8*)(sK + tok * 136 + d8 * 8) = rK[it];
    }
#pragma unroll
    for (int it = 0; it < 2; ++it) {
      int f = tid + it * 256;
      int tok = f & 31, d8 = f >> 5;
      U8 u; u.v = rV[it];
#pragma unroll
      for (int j = 0; j < 8; ++j) sV[(d8 * 8 + j) * 40 + tok] = u.s[j];
    }
  };

  if (len > 0) load_tile(0);
  for (int t0 = 0; t0 < len; t0 += 32) {
    __syncthreads();
    store_tile();
    __syncthreads();
    if (t0 + 32 < len) load_tile(t0 + 32);
    int nv = len - t0; if (nv > 32) nv = 32;
    floatx4 sS[2];
    sS[0] = (floatx4){0.f, 0.f, 0.f, 0.f};
    sS[1] = (floatx4){0.f, 0.f, 0.f, 0.f};
#pragma unroll
    for (int g = 0; g < 2; ++g)
#pragma unroll
      for (int c = 0; c < 4; ++c) {
        short8 kB = *(const short8*)(sK + (g * 16 + m) * 136 + c * 32 + quad * 8);
        sS[g] = __builtin_amdgcn_mfma_f32_16x16x32_bf16(qA[c], kB, sS[g], 0, 0, 0);
      }
#pragma unroll
    for (int g = 0; g < 2; ++g) {
      bool valid = (g * 16 + m) < nv;
#pragma unroll
      for (int r = 0; r < 4; ++r) {
        float p = valid ? __expf(sS[g][r]) : 0.f;
        lp[r] += p;
        sP[(w * 16 + quad * 4 + r) * 40 + g * 16 + m] = f2bf(p);
      }
    }
    short8 pA = *(const short8*)(sP + (w * 16 + m) * 40 + quad * 8);
#pragma unroll
    for (int dg = 0; dg < 8; ++dg) {
      short8 vB = *(const short8*)(sV + (dg * 16 + m) * 40 + quad * 8);
      oA[dg] = __builtin_amdgcn_mfma_f32_16x16x32_bf16(pA, vB, oA[dg], 0, 0, 0);
    }
  }

#pragma unroll
  for (int r = 0; r < 4; ++r) {
    float v = lp[r];
    v += __shfl_xor(v, 1); v += __shfl_xor(v, 2);
    v += __shfl_xor(v, 4); v += __shfl_xor(v, 8);
    lp[r] = v;
  }
  if (m == 0) {
#pragma unroll
    for (int r = 0; r < 4; ++r)
      lpart[w * 16 + quad * 4 + r] = lp[r];
  }
#pragma unroll
  for (int dg = 0; dg < 8; ++dg)
#pragma unroll
    for (int r = 0; r < 4; ++r)
      part[(w * 16 + quad * 4 + r) * 128 + dg * 16 + m] = f2bf(oA[dg][r]);
}

// ---------------- MFMA post ----------------
__global__ __launch_bounds__(256) void post_kernel(
    const unsigned short* __restrict__ pd, const float* __restrict__ ldv,
    const unsigned short* __restrict__ pe, const float* __restrict__ lev,
    const unsigned short* __restrict__ Wl,
    const float* __restrict__ bv_d, const float* __restrict__ ob_d,
    const float* __restrict__ bv_e, const float* __restrict__ ob_e,
    const float* __restrict__ ln2g, const float* __restrict__ ln2b,
    const float* __restrict__ b1, const float* __restrict__ b2,
    float* __restrict__ lat) {
  const unsigned short* wv_d = Wl;
  const unsigned short* ow_d = Wl + 16384;
  const unsigned short* wv_e = Wl + 32768;
  const unsigned short* ow_e = Wl + 49152;
  const unsigned short* w1   = Wl + 65536;
  const unsigned short* w2   = Wl + 98304;

  __shared__ __align__(16) unsigned short sX[64 * 136];
  __shared__ __align__(16) unsigned short sVH[16 * 136];
  __shared__ __align__(16) unsigned short sF[16 * 264];
  __shared__ __align__(16) float sAcc[16 * 132];
  __shared__ float sLd[64], sLe[64];

  const int tid = threadIdx.x;
  const int b = blockIdx.x;
  const int lane = tid & 63;
  const int w = tid >> 6;
  const int m = lane & 15;
  const int quad = lane >> 4;

  if (tid < 64) {
    float v = ldv[(size_t)b * 64 + tid];
    sLd[tid] = (v > 0.f) ? 1.f / v : 0.f;
  } else if (tid < 128) {
    int r = tid - 64;
    float v = lev[((size_t)b * 4 + 0) * 64 + r] + lev[((size_t)b * 4 + 1) * 64 + r]
            + lev[((size_t)b * 4 + 2) * 64 + r] + lev[((size_t)b * 4 + 3) * 64 + r];
    sLe[r] = (v > 0.f) ? 1.f / v : 0.f;
  }
  __syncthreads();
  {
    const ushort4* src = (const ushort4*)(pd + (size_t)b * 8192);
#pragma unroll
    for (int it = 0; it < 8; ++it) {
      int f = tid + it * 256;
      int row = f >> 5, d = (f & 31) * 4;
      ushort4 u = src[f];
      float sc = sLd[row];
      ushort4 o = { f2bf(bf2f(u.x) * sc), f2bf(bf2f(u.y) * sc),
                    f2bf(bf2f(u.z) * sc), f2bf(bf2f(u.w) * sc) };
      *(ushort4*)(sX + row * 136 + d) = o;
    }
  }
  __syncthreads();
  {
    short8 aF[4];
    const unsigned short* arow = sX + (w * 16 + m) * 136 + quad * 8;
#pragma unroll
    for (int c = 0; c < 4; ++c) aF[c] = *(const short8*)(arow + c * 32);
#pragma unroll
    for (int t = 0; t < 2; ++t) {
      int n = w * 32 + t * 16 + m;
      floatx4 acc = (floatx4){0.f, 0.f, 0.f, 0.f};
      const unsigned short* brow = wv_d + n * 128 + quad * 8;
#pragma unroll
      for (int c = 0; c < 4; ++c)
        acc = __builtin_amdgcn_mfma_f32_16x16x32_bf16(aF[c], *(const short8*)(brow + c * 32), acc, 0, 0, 0);
      float bb = bv_d[n];
#pragma unroll
      for (int r = 0; r < 4; ++r) sVH[(quad * 4 + r) * 136 + n] = f2bf(acc[r] + bb);
    }
  }
  __syncthreads();
  {
    short8 aF[4];
    const unsigned short* arow = sVH + m * 136 + quad * 8;
#pragma unroll
    for (int c = 0; c < 4; ++c) aF[c] = *(const short8*)(arow + c * 32);
#pragma unroll
    for (int t = 0; t < 2; ++t) {
      int n = w * 32 + t * 16 + m;
      floatx4 acc = (floatx4){0.f, 0.f, 0.f, 0.f};
      const unsigned short* brow = ow_d + n * 128 + quad * 8;
#pragma unroll
      for (int c = 0; c < 4; ++c)
        acc = __builtin_amdgcn_mfma_f32_16x16x32_bf16(aF[c], *(const short8*)(brow + c * 32), acc, 0, 0, 0);
      float bb = ob_d[n];
#pragma unroll
      for (int r = 0; r < 4; ++r) {
        int q = quad * 4 + r;
        sAcc[q * 132 + n] = lat[(size_t)b * 2048 + q * 128 + n] + acc[r] + bb;
      }
    }
  }
  __syncthreads();
  {
    const ushort4* s0 = (const ushort4*)(pe + ((size_t)b * 4 + 0) * 8192);
    const ushort4* s1 = (const ushort4*)(pe + ((size_t)b * 4 + 1) * 8192);
    const ushort4* s2 = (const ushort4*)(pe + ((size_t)b * 4 + 2) * 8192);
    const ushort4* s3 = (const ushort4*)(pe + ((size_t)b * 4 + 3) * 8192);
#pragma unroll
    for (int it = 0; it < 8; ++it) {
      int f = tid + it * 256;
      int row = f >> 5, d = (f & 31) * 4;
      ushort4 u0 = s0[f], u1 = s1[f], u2 = s2[f], u3 = s3[f];
      float sc = sLe[row];
      ushort4 o = { f2bf((bf2f(u0.x) + bf2f(u1.x) + bf2f(u2.x) + bf2f(u3.x)) * sc),
                    f2bf((bf2f(u0.y) + bf2f(u1.y) + bf2f(u2.y) + bf2f(u3.y)) * sc),
                    f2bf((bf2f(u0.z) + bf2f(u1.z) + bf2f(u2.z) + bf2f(u3.z)) * sc),
                    f2bf((bf2f(u0.w) + bf2f(u1.w) + bf2f(u2.w) + bf2f(u3.w)) * sc) };
      *(ushort4*)(sX + row * 136 + d) = o;
    }
  }
  __syncthreads();
  {
    short8 aF[4];
    const unsigned short* arow = sX + (w * 16 + m) * 136 + quad * 8;
#pragma unroll
    for (int c = 0; c < 4; ++c) aF[c] = *(const short8*)(arow + c * 32);
#pragma unroll
    for (int t = 0; t < 2; ++t) {
      int n = w * 32 + t * 16 + m;
      floatx4 acc = (floatx4){0.f, 0.f, 0.f, 0.f};
      const unsigned short* brow = wv_e + n * 128 + quad * 8;
#pragma unroll
      for (int c = 0; c < 4; ++c)
        acc = __builtin_amdgcn_mfma_f32_16x16x32_bf16(aF[c], *(const short8*)(brow + c * 32), acc, 0, 0, 0);
      float bb = bv_e[n];
#pragma unroll
      for (int r = 0; r < 4; ++r) sVH[(quad * 4 + r) * 136 + n] = f2bf(acc[r] + bb);
    }
  }
  __syncthreads();
  {
    short8 aF[4];
    const unsigned short* arow = sVH + m * 136 + quad * 8;
#pragma unroll
    for (int c = 0; c < 4; ++c) aF[c] = *(const short8*)(arow + c * 32);
#pragma unroll
    for (int t = 0; t < 2; ++t) {
      int n = w * 32 + t * 16 + m;
      floatx4 acc = (floatx4){0.f, 0.f, 0.f, 0.f};
      const unsigned short* brow = ow_e + n * 128 + quad * 8;
#pragma unroll
      for (int c = 0; c < 4; ++c)
        acc = __builtin_amdgcn_mfma_f32_16x16x32_bf16(aF[c], *(const short8*)(brow + c * 32), acc, 0, 0, 0);
      float bb = ob_e[n];
#pragma unroll
      for (int r = 0; r < 4; ++r) {
        int q = quad * 4 + r;
        sAcc[q * 132 + n] += acc[r] + bb;
      }
    }
  }
  __syncthreads();
  {
    int q = tid >> 4, li = tid & 15, d0 = li * 8;
    float x[8];
#pragma unroll
    for (int j = 0; j < 8; ++j) x[j] = sAcc[q * 132 + d0 + j];
    float s1 = 0.f, s2 = 0.f;
#pragma unroll
    for (int j = 0; j < 8; ++j) { s1 += x[j]; s2 += x[j] * x[j]; }
#pragma unroll
    for (int o = 1; o < 16; o <<= 1) { s1 += __shfl_xor(s1, o); s2 += __shfl_xor(s2, o); }
    float mean = s1 * (1.f / 128.f);
    float var = s2 * (1.f / 128.f) - mean * mean;
    float rstd = rsqrtf(var + 1e-5f);
    float y[8];
#pragma unroll
    for (int j = 0; j < 8; ++j)
      y[j] = (x[j] - mean) * rstd * ln2g[d0 + j] + ln2b[d0 + j];
    ushort4 o0 = { f2bf(y[0]), f2bf(y[1]), f2bf(y[2]), f2bf(y[3]) };
    ushort4 o1 = { f2bf(y[4]), f2bf(y[5]), f2bf(y[6]), f2bf(y[7]) };
    *(ushort4*)(sX + q * 136 + d0) = o0;
    *(ushort4*)(sX + q * 136 + d0 + 4) = o1;
  }
  __syncthreads();
  {
    short8 aF[4];
    const unsigned short* arow = sX + m * 136 + quad * 8;
#pragma unroll
    for (int c = 0; c < 4; ++c) aF[c] = *(const short8*)(arow + c * 32);
#pragma unroll
    for (int t = 0; t < 4; ++t) {
      int n = w * 64 + t * 16 + m;
      floatx4 acc = (floatx4){0.f, 0.f, 0.f, 0.f};
      const unsigned short* brow = w1 + n * 128 + quad * 8;
#pragma unroll
      for (int c = 0; c < 4; ++c)
        acc = __builtin_amdgcn_mfma_f32_16x16x32_bf16(aF[c], *(const short8*)(brow + c * 32), acc, 0, 0, 0);
      float bb = b1[n];
#pragma unroll
      for (int r = 0; r < 4; ++r)
        sF[(quad * 4 + r) * 264 + n] = f2bf(fmaxf(acc[r] + bb, 0.f));
    }
  }
  __syncthreads();
  {
    short8 aF[8];
    const unsigned short* arow = sF + m * 264 + quad * 8;
#pragma unroll
    for (int c = 0; c < 8; ++c) aF[c] = *(const short8*)(arow + c * 32);
#pragma unroll
    for (int t = 0; t < 2; ++t) {
      int n = w * 32 + t * 16 + m;
      floatx4 acc = (floatx4){0.f, 0.f, 0.f, 0.f};
      const unsigned short* brow = w2 + n * 256 + quad * 8;
#pragma unroll
      for (int c = 0; c < 8; ++c)
        acc = __builtin_amdgcn_mfma_f32_16x16x32_bf16(aF[c], *(const short8*)(brow + c * 32), acc, 0, 0, 0);
      float bb = b2[n];
#pragma unroll
      for (int r = 0; r < 4; ++r) {
        int q = quad * 4 + r;
        lat[(size_t)b * 2048 + q * 128 + n] = sAcc[q * 132 + n] + acc[r] + bb;
      }
    }
  }
}

// ---------------- head ----------------
__global__ __launch_bounds__(256) void head_kernel(const float* __restrict__ lat,
                                                   const float* __restrict__ w1,
                                                   const float* __restrict__ b1,
                                                   const float* __restrict__ w2,
                                                   const float* __restrict__ b2,
                                                   float* __restrict__ out) {
  __shared__ __align__(16) float sX[2048];
  __shared__ float sH[128];
  const int tid = threadIdx.x;
  const int b = blockIdx.x;
  {
    const float4* src = (const float4*)(lat + (size_t)b * 2048);
#pragma unroll
    for (int it = 0; it < 2; ++it) ((float4*)sX)[tid + it * 256] = src[tid + it * 256];
  }
  __syncthreads();
  {
    int o = tid >> 1, kh = tid & 1;
    float a = 0.f;
    const float* wr = w1 + (size_t)o * 2048 + kh * 1024;
    const float* xb = sX + kh * 1024;
    for (int k4 = 0; k4 < 256; ++k4) {
      float4 w4 = *(const float4*)(wr + k4 * 4);
      float4 x4 = *(const float4*)(xb + k4 * 4);
      a += w4.x * x4.x + w4.y * x4.y + w4.z * x4.z + w4.w * x4.w;
    }
    a += __shfl_xor(a, 1);
    if (kh == 0) sH[o] = fmaxf(a + b1[o], 0.f);
  }
  __syncthreads();
  if (tid < 64) {
    float a = sH[tid] * w2[tid] + sH[tid + 64] * w2[tid + 64];
#pragma unroll
    for (int o = 1; o < 64; o <<= 1) a += __shfl_xor(a, o);
    if (tid == 0) {
      float x = a + b2[0];
      out[b] = (x > 20.f) ? x : log1pf(__expf(x));
    }
  }
}

extern "C" void kernel_launch(void* const* d_in, const int* in_sizes, int n_in,
                              void* d_out, int out_size, void* d_ws, size_t ws_size,
                              hipStream_t stream) {
  const float* drug_k  = (const float*)d_in[0];
  const float* drug_v  = (const float*)d_in[1];
  const float* enz_k   = (const float*)d_in[2];
  const float* enz_v   = (const float*)d_in[3];
  const int*   drug_b  = (const int*)d_in[4];
  const int*   enz_b   = (const int*)d_in[5];
  const float* latents = (const float*)d_in[6];
  const float* wq_d    = (const float*)d_in[7];
  const float* bq_d    = (const float*)d_in[8];
  const float* wq_e    = (const float*)d_in[9];
  const float* bq_e    = (const float*)d_in[10];
  const float* mha_d_w = (const float*)d_in[11];
  const float* mha_d_b = (const float*)d_in[12];
  const float* mha_d_ow= (const float*)d_in[13];
  const float* mha_d_ob= (const float*)d_in[14];
  const float* mha_e_w = (const float*)d_in[15];
  const float* mha_e_b = (const float*)d_in[16];
  const float* mha_e_ow= (const float*)d_in[17];
  const float* mha_e_ob= (const float*)d_in[18];
  const float* ln1_g   = (const float*)d_in[19];
  const float* ln1_b   = (const float*)d_in[20];
  const float* ln2_g   = (const float*)d_in[21];
  const float* ln2_b   = (const float*)d_in[22];
  const float* ffn_w1  = (const float*)d_in[23];
  const float* ffn_b1  = (const float*)d_in[24];
  const float* ffn_w2  = (const float*)d_in[25];
  const float* ffn_b2  = (const float*)d_in[26];
  const float* head_w1 = (const float*)d_in[27];
  const float* head_b1 = (const float*)d_in[28];
  const float* head_w2 = (const float*)d_in[29];
  const float* head_b2 = (const float*)d_in[30];
  float* out = (float*)d_out;

  const int n_dk = in_sizes[0];   // 25600*128
  const int n_ek = in_sizes[2];   // 153600*128

  int* seg = (int*)d_ws;
  float* fws = (float*)d_ws;
  float* Wqf = fws + 2048;
  float* bqf = Wqf + 131072;
  float* lat = bqf + 1024;
  float* l_d = lat + 1048576;
  float* l_e = l_d + 32768;
  unsigned short* Qt     = (unsigned short*)(l_e + 131072);
  unsigned short* part_d = Qt + 8388608;
  unsigned short* part_e = part_d + 4194304;
  unsigned short* Kd_bf  = part_e + 16777216;
  unsigned short* Vd_bf  = Kd_bf + n_dk;
  unsigned short* Ke_bf  = Vd_bf + n_dk;
  unsigned short* Ve_bf  = Ke_bf + n_ek;
  unsigned short* Wbf    = Ve_bf + n_ek;

  seg_kernel<<<2, 512, 0, stream>>>(drug_b, in_sizes[4], enz_b, in_sizes[5], seg);
  init_lat_kernel<<<1024, 256, 0, stream>>>(latents, lat);
  fold_kernel<<<64, 256, 0, stream>>>(wq_d, bq_d, wq_e, bq_e,
                                      mha_d_w, mha_d_b, mha_e_w, mha_e_b, Wqf, bqf);
  cvt_kernel<<<(n_dk / 4 + 255) / 256, 256, 0, stream>>>(drug_k, Kd_bf, n_dk / 4);
  cvt_kernel<<<(n_dk / 4 + 255) / 256, 256, 0, stream>>>(drug_v, Vd_bf, n_dk / 4);
  cvt_kernel<<<(n_ek / 4 + 255) / 256, 256, 0, stream>>>(enz_k, Ke_bf, n_ek / 4);
  cvt_kernel<<<(n_ek / 4 + 255) / 256, 256, 0, stream>>>(enz_v, Ve_bf, n_ek / 4);
  cvtw_kernel<<<512, 256, 0, stream>>>(mha_d_w, mha_d_ow, mha_e_w, mha_e_ow,
                                       ffn_w1, ffn_w2, Wbf);
  for (int l = 0; l < 4; ++l) {
    qtilde_kernel<<<512, 256, 0, stream>>>(lat, ln1_g + l * 128, ln1_b + l * 128,
        Wqf + (size_t)l * 32768, bqf + l * 256,
        mha_d_w + (size_t)l * 49152 + 16384, mha_e_w + (size_t)l * 49152 + 16384, Qt);
    attn3_kernel<<<2560, 256, 0, stream>>>(Kd_bf, Vd_bf, Ke_bf, Ve_bf, seg,
        Qt, part_d, l_d, part_e, l_e);
    post_kernel<<<512, 256, 0, stream>>>(part_d, l_d, part_e, l_e,
        Wbf + (size_t)l * 131072,
        mha_d_b + l * 384 + 256, mha_d_ob + l * 128,
        mha_e_b + l * 384 + 256, mha_e_ob + l * 128,
        ln2_g + l * 128, ln2_b + l * 128,
        ffn_b1 + l * 256, ffn_b2 + l * 128,
        lat);
  }
  head_kernel<<<512, 256, 0, stream>>>(lat, head_w1, head_b1, head_w2, head_b2, out);
}

// Round 5
// 623.233 us; speedup vs baseline: 3.1883x; 1.4139x over previous
//
#include <hip/hip_runtime.h>
#include <math.h>

#define NL 16
#define DD 128

typedef __attribute__((ext_vector_type(8))) short short8;
typedef __attribute__((ext_vector_type(4))) float floatx4;

union U8 { short8 v; unsigned short s[8]; };

__device__ __forceinline__ unsigned short f2bf(float x) {
  union { float f; unsigned u; } v; v.f = x; return (unsigned short)(v.u >> 16);
}
__device__ __forceinline__ float bf2f(unsigned short s) {
  union { unsigned u; float f; } v; v.u = ((unsigned)s) << 16; return v.f;
}

// ---------------- segment table ----------------
__global__ void seg_kernel(const int* __restrict__ db, int nd,
                           const int* __restrict__ eb, int ne,
                           int* __restrict__ seg) {
  const int* arr = (blockIdx.x == 0) ? db : eb;
  int n = (blockIdx.x == 0) ? nd : ne;
  int* start = seg + blockIdx.x * 1024;
  int* cnt = start + 512;
  int b = threadIdx.x;
  if (b < 512) {
    int lo = 0, hi = n;
    while (lo < hi) { int mid = (lo + hi) >> 1; if (arr[mid] < b) lo = mid + 1; else hi = mid; }
    int s = lo;
    lo = s; hi = n;
    while (lo < hi) { int mid = (lo + hi) >> 1; if (arr[mid] < b + 1) lo = mid + 1; else hi = mid; }
    start[b] = s; cnt[b] = lo - s;
  }
}

// ---------------- lat init (float4) ----------------
__global__ void init_lat_kernel(const float* __restrict__ latents, float* __restrict__ lat) {
  int i = blockIdx.x * blockDim.x + threadIdx.x;
  ((float4*)lat)[i] = ((const float4*)latents)[i & 511];
}

// ---------------- fp32 -> bf16 convert, 4 arrays in one launch ----------------
__global__ void cvt4_kernel(const float* __restrict__ a, unsigned short* __restrict__ da, int na4,
                            const float* __restrict__ b, unsigned short* __restrict__ db, int nb4,
                            const float* __restrict__ c, unsigned short* __restrict__ dc, int nc4,
                            const float* __restrict__ d, unsigned short* __restrict__ dd, int nd4) {
  int i = blockIdx.x * blockDim.x + threadIdx.x;
  const float* s; unsigned short* o; int r;
  if (i < na4)                        { s = a; o = da; r = i; }
  else if (i < na4 + nb4)             { s = b; o = db; r = i - na4; }
  else if (i < na4 + nb4 + nc4)       { s = c; o = dc; r = i - na4 - nb4; }
  else if (i < na4 + nb4 + nc4 + nd4) { s = d; o = dd; r = i - na4 - nb4 - nc4; }
  else return;
  float4 v = ((const float4*)s)[r];
  ushort4 u = { f2bf(v.x), f2bf(v.y), f2bf(v.z), f2bf(v.w) };
  ((ushort4*)o)[r] = u;
}

// convert post weights to bf16, per-layer contiguous blocks
__global__ void cvtw_kernel(const float* __restrict__ mw_d, const float* __restrict__ ow_d,
                            const float* __restrict__ mw_e, const float* __restrict__ ow_e,
                            const float* __restrict__ w1, const float* __restrict__ w2,
                            unsigned short* __restrict__ Wbf) {
  int l = blockIdx.x >> 7, blk = blockIdx.x & 127;
  int idx = blk * 1024 + threadIdx.x * 4;
  const float* src; int off;
  if (idx < 16384)      { src = mw_d + (size_t)l * 49152 + 32768; off = idx; }
  else if (idx < 32768) { src = ow_d + (size_t)l * 16384; off = idx - 16384; }
  else if (idx < 49152) { src = mw_e + (size_t)l * 49152 + 32768; off = idx - 32768; }
  else if (idx < 65536) { src = ow_e + (size_t)l * 16384; off = idx - 49152; }
  else if (idx < 98304) { src = w1 + (size_t)l * 32768; off = idx - 65536; }
  else                  { src = w2 + (size_t)l * 32768; off = idx - 98304; }
  float4 v = *(const float4*)(src + off);
  ushort4 o = { f2bf(v.x), f2bf(v.y), f2bf(v.z), f2bf(v.w) };
  *(ushort4*)(Wbf + (size_t)l * 131072 + idx) = o;
}

// ---------------- fold: Wqf = mwq @ wq (scaled), fp32 ----------------
__global__ __launch_bounds__(256) void fold_kernel(
    const float* __restrict__ wq_d, const float* __restrict__ bq_d,
    const float* __restrict__ wq_e, const float* __restrict__ bq_e,
    const float* __restrict__ mw_d, const float* __restrict__ mb_d,
    const float* __restrict__ mw_e, const float* __restrict__ mb_e,
    float* __restrict__ Wqf, float* __restrict__ bqf) {
  __shared__ __align__(16) float sMW[2048];
  const int pb = blockIdx.x >> 3, rg = blockIdx.x & 7;
  const int l = pb >> 1, p = pb & 1;
  const float* wq = (p == 0 ? wq_d : wq_e) + (size_t)l * 16384;
  const float* bq = (p == 0 ? bq_d : bq_e) + l * 128;
  const float* mw = (p == 0 ? mw_d : mw_e) + (size_t)l * 49152;
  const float* mb = (p == 0 ? mb_d : mb_e) + l * 384;
  const float scale = 0.17677669529663687f;
  const int tid = threadIdx.x;
  {
    const float4* src = (const float4*)(mw + rg * 2048);
    ((float4*)sMW)[tid] = src[tid];
    ((float4*)sMW)[tid + 256] = src[tid + 256];
  }
  __syncthreads();
  const int j = tid & 127, ih = tid >> 7;
  float acc[8];
#pragma unroll
  for (int r = 0; r < 8; ++r) acc[r] = 0.f;
#pragma unroll 4
  for (int k = 0; k < 128; ++k) {
    float wv = wq[k * 128 + j];
#pragma unroll
    for (int r = 0; r < 8; ++r) acc[r] += sMW[(ih * 8 + r) * 128 + k] * wv;
  }
  float* W = Wqf + (size_t)pb * 16384 + (rg * 16 + ih * 8) * 128 + j;
#pragma unroll
  for (int r = 0; r < 8; ++r) W[r * 128] = acc[r] * scale;
  if (rg == 0 && tid < 128) {
    float s = 0.f;
    const float* mr = mw + tid * 128;
    for (int k = 0; k < 128; ++k) s += mr[k] * bq[k];
    bqf[pb * 128 + tid] = (s + mb[tid]) * scale;
  }
}

// ---------------- wt: WtT[(l,p,h,d)][k] = sum_j Wqf[h*32+j][k]*wk[h*32+j][d], stored in
// MFMA B-frag order; bt[(l,p,h,d)] = sum_j bqf[h*32+j]*wk[h*32+j][d] ----------------
__global__ __launch_bounds__(256) void wt_kernel(
    const float* __restrict__ Wqf, const float* __restrict__ bqf,
    const float* __restrict__ mw_d, const float* __restrict__ mw_e,
    unsigned short* __restrict__ WtB, float* __restrict__ bt) {
  const int l = blockIdx.x >> 3, p = (blockIdx.x >> 2) & 1, h = blockIdx.x & 3;
  const float* wqf = Wqf + (size_t)(l * 2 + p) * 16384 + (h * 32) * 128;
  const float* wk  = (p == 0 ? mw_d : mw_e) + (size_t)l * 49152 + 16384 + (h * 32) * 128;
  const float* bqv = bqf + (l * 2 + p) * 128 + h * 32;
  __shared__ __align__(16) float sWq[4096];
  __shared__ __align__(16) float sWk[4096];
  __shared__ float sBq[32];
  const int tid = threadIdx.x;
  for (int i = tid; i < 1024; i += 256) {
    ((float4*)sWq)[i] = ((const float4*)wqf)[i];
    ((float4*)sWk)[i] = ((const float4*)wk)[i];
  }
  if (tid < 32) sBq[tid] = bqv[tid];
  __syncthreads();
  const int d = tid & 127, kh = tid >> 7;
  const int n = p * 512 + h * 128 + d;
  const int tn = n >> 4, m = n & 15;
  unsigned short* outl = WtB + (size_t)l * 131072;
#pragma unroll
  for (int kc = 0; kc < 4; ++kc) {
    int k0 = kh * 64 + kc * 16;
    float acc[16];
#pragma unroll
    for (int kk = 0; kk < 16; ++kk) acc[kk] = 0.f;
    for (int j = 0; j < 32; ++j) {
      float wkd = sWk[j * 128 + d];
#pragma unroll
      for (int kk = 0; kk < 16; ++kk) acc[kk] += sWq[j * 128 + k0 + kk] * wkd;
    }
#pragma unroll
    for (int kk = 0; kk < 16; ++kk) {
      int k = k0 + kk;
      int c = k >> 5, quad = (k >> 3) & 3, j8 = k & 7;
      int lane = quad * 16 + m;
      outl[(((size_t)tn * 4 + c) * 64 + lane) * 8 + j8] = f2bf(acc[kk]);
    }
  }
  if (kh == 0) {
    float a = 0.f;
    for (int j = 0; j < 32; ++j) a += sBq[j] * sWk[j * 128 + d];
    bt[l * 1024 + n] = a;
  }
}

// ---------------- per-layer Q~: LN1 + single MFMA GEMM vs pre-folded Wt ----------------
__global__ __launch_bounds__(256) void qtilde_kernel(
    const float* __restrict__ lat,
    const float* __restrict__ lng, const float* __restrict__ lnb,
    const unsigned short* __restrict__ WtBl, const float* __restrict__ btl,
    unsigned short* __restrict__ Qt) {
  __shared__ __align__(16) unsigned short sNL[16 * 136];
  const int tid = threadIdx.x;
  const int b = blockIdx.x;
  // LN1 -> bf16 LDS
  {
    int q = tid >> 4, li = tid & 15, d0 = li * 8;
    const float* xr = lat + ((size_t)b * NL + q) * DD + d0;
    float x[8];
    *(float4*)(x) = *(const float4*)(xr);
    *(float4*)(x + 4) = *(const float4*)(xr + 4);
    float s1 = 0.f, s2 = 0.f;
#pragma unroll
    for (int j = 0; j < 8; ++j) { s1 += x[j]; s2 += x[j] * x[j]; }
#pragma unroll
    for (int o = 1; o < 16; o <<= 1) { s1 += __shfl_xor(s1, o); s2 += __shfl_xor(s2, o); }
    float mean = s1 * (1.f / 128.f);
    float var = s2 * (1.f / 128.f) - mean * mean;
    float rstd = rsqrtf(var + 1e-5f);
    float y[8];
#pragma unroll
    for (int j = 0; j < 8; ++j)
      y[j] = (x[j] - mean) * rstd * lng[d0 + j] + lnb[d0 + j];
    ushort4 o0 = { f2bf(y[0]), f2bf(y[1]), f2bf(y[2]), f2bf(y[3]) };
    ushort4 o1 = { f2bf(y[4]), f2bf(y[5]), f2bf(y[6]), f2bf(y[7]) };
    *(ushort4*)(sNL + q * 136 + d0) = o0;
    *(ushort4*)(sNL + q * 136 + d0 + 4) = o1;
  }
  __syncthreads();
  const int lane = tid & 63, w = tid >> 6, m = lane & 15, quad = lane >> 4;
  short8 aF[4];
  {
    const unsigned short* arow = sNL + m * 136 + quad * 8;
#pragma unroll
    for (int c = 0; c < 4; ++c) aF[c] = *(const short8*)(arow + c * 32);
  }
  unsigned short* qtb = Qt + (size_t)b * 16384;
#pragma unroll
  for (int t = 0; t < 16; ++t) {
    int tn = w * 16 + t;
    floatx4 acc = (floatx4){0.f, 0.f, 0.f, 0.f};
#pragma unroll
    for (int c = 0; c < 4; ++c) {
      short8 bF = *(const short8*)(WtBl + (((size_t)tn * 4 + c) * 64 + lane) * 8);
      acc = __builtin_amdgcn_mfma_f32_16x16x32_bf16(aF[c], bF, acc, 0, 0, 0);
    }
    int n = tn * 16 + m;
    float bb = btl[n];
    int p = n >> 9, h = (n >> 7) & 3, d = n & 127;
    unsigned short* op = qtb + (p * 64 + h * 16) * 128 + d;
#pragma unroll
    for (int r = 0; r < 4; ++r) op[(quad * 4 + r) * 128] = f2bf(acc[r] + bb);
  }
}

// ---------------- fused MFMA flash attention (bf16 K/V), drug + enzyme(x4 split) ----------------
__global__ __launch_bounds__(256, 4) void attn3_kernel(
    const unsigned short* __restrict__ Kd, const unsigned short* __restrict__ Vd,
    const unsigned short* __restrict__ Ke, const unsigned short* __restrict__ Ve,
    const int* __restrict__ seg,
    const unsigned short* __restrict__ Qt,
    unsigned short* __restrict__ part_d, float* __restrict__ l_d,
    unsigned short* __restrict__ part_e, float* __restrict__ l_e) {
  __shared__ __align__(16) unsigned short sK[32 * 136];
  __shared__ __align__(16) unsigned short sV[128 * 40];
  __shared__ __align__(16) unsigned short sP[64 * 40];
  const int tid = threadIdx.x;
  const int bi = blockIdx.x;

  const unsigned short* Kp; const unsigned short* Vp;
  const unsigned short* qt;
  unsigned short* part; float* lpart;
  int len, st;
  if (bi < 2048) {
    int b = bi >> 2, sp = bi & 3;
    int n = seg[1536 + b]; if (n > 512) n = 512;
    int chunk = (n + 3) >> 2;
    int begin = sp * chunk;
    len = n - begin; if (len > chunk) len = chunk; if (len < 0) len = 0;
    st = seg[1024 + b] + begin;
    Kp = Ke; Vp = Ve;
    qt = Qt + ((size_t)b * 2 + 1) * 8192;
    part = part_e + (size_t)bi * 8192;
    lpart = l_e + (size_t)bi * 64;
  } else {
    int b = bi - 2048;
    int n = seg[512 + b]; if (n > 128) n = 128;
    len = n;
    st = seg[b];
    Kp = Kd; Vp = Vd;
    qt = Qt + (size_t)b * 2 * 8192;
    part = part_d + (size_t)b * 8192;
    lpart = l_d + (size_t)b * 64;
  }

  const int lane = tid & 63;
  const int w = tid >> 6;
  const int m = lane & 15;
  const int quad = lane >> 4;

  short8 qA[4];
  {
    const unsigned short* qrow = qt + (size_t)(w * 16 + m) * 128 + quad * 8;
#pragma unroll
    for (int c = 0; c < 4; ++c) qA[c] = *(const short8*)(qrow + c * 32);
  }

  floatx4 oA[8];
#pragma unroll
  for (int i = 0; i < 8; ++i) oA[i] = (floatx4){0.f, 0.f, 0.f, 0.f};
  float lp[4] = {0.f, 0.f, 0.f, 0.f};

  short8 rK[2], rV[2];
  const short8 z8 = {0, 0, 0, 0, 0, 0, 0, 0};
  auto load_tile = [&](int t0) {
    int nv = len - t0; if (nv > 32) nv = 32;
#pragma unroll
    for (int it = 0; it < 2; ++it) {
      int f = tid + it * 256;
      int tok = f >> 4, d8 = f & 15;
      rK[it] = (tok < nv) ? *(const short8*)(Kp + (size_t)(st + t0 + tok) * 128 + d8 * 8) : z8;
    }
#pragma unroll
    for (int it = 0; it < 2; ++it) {
      int f = tid + it * 256;
      int tok = f & 31, d8 = f >> 5;
      rV[it] = (tok < nv) ? *(const short8*)(Vp + (size_t)(st + t0 + tok) * 128 + d8 * 8) : z8;
    }
  };
  auto store_tile = [&]() {
#pragma unroll
    for (int it = 0; it < 2; ++it) {
      int f = tid + it * 256;
      int tok = f >> 4, d8 = f & 15;
      *(short8*)(sK + tok * 136 + d8 * 8) = rK[it];
    }
#pragma unroll
    for (int it = 0; it < 2; ++it) {
      int f = tid + it * 256;
      int tok = f & 31, d8 = f >> 5;
      U8 u; u.v = rV[it];
#pragma unroll
      for (int j = 0; j < 8; ++j) sV[(d8 * 8 + j) * 40 + tok] = u.s[j];
    }
  };

  if (len > 0) load_tile(0);
  for (int t0 = 0; t0 < len; t0 += 32) {
    __syncthreads();
    store_tile();
    __syncthreads();
    if (t0 + 32 < len) load_tile(t0 + 32);
    int nv = len - t0; if (nv > 32) nv = 32;
    floatx4 sS[2];
    sS[0] = (floatx4){0.f, 0.f, 0.f, 0.f};
    sS[1] = (floatx4){0.f, 0.f, 0.f, 0.f};
#pragma unroll
    for (int g = 0; g < 2; ++g)
#pragma unroll
      for (int c = 0; c < 4; ++c) {
        short8 kB = *(const short8*)(sK + (g * 16 + m) * 136 + c * 32 + quad * 8);
        sS[g] = __builtin_amdgcn_mfma_f32_16x16x32_bf16(qA[c], kB, sS[g], 0, 0, 0);
      }
#pragma unroll
    for (int g = 0; g < 2; ++g) {
      bool valid = (g * 16 + m) < nv;
#pragma unroll
      for (int r = 0; r < 4; ++r) {
        float p = valid ? __expf(sS[g][r]) : 0.f;
        lp[r] += p;
        sP[(w * 16 + quad * 4 + r) * 40 + g * 16 + m] = f2bf(p);
      }
    }
    short8 pA = *(const short8*)(sP + (w * 16 + m) * 40 + quad * 8);
#pragma unroll
    for (int dg = 0; dg < 8; ++dg) {
      short8 vB = *(const short8*)(sV + (dg * 16 + m) * 40 + quad * 8);
      oA[dg] = __builtin_amdgcn_mfma_f32_16x16x32_bf16(pA, vB, oA[dg], 0, 0, 0);
    }
  }

#pragma unroll
  for (int r = 0; r < 4; ++r) {
    float v = lp[r];
    v += __shfl_xor(v, 1); v += __shfl_xor(v, 2);
    v += __shfl_xor(v, 4); v += __shfl_xor(v, 8);
    lp[r] = v;
  }
  if (m == 0) {
#pragma unroll
    for (int r = 0; r < 4; ++r)
      lpart[w * 16 + quad * 4 + r] = lp[r];
  }
#pragma unroll
  for (int dg = 0; dg < 8; ++dg)
#pragma unroll
    for (int r = 0; r < 4; ++r)
      part[(w * 16 + quad * 4 + r) * 128 + dg * 16 + m] = f2bf(oA[dg][r]);
}

// ---------------- MFMA post ----------------
__global__ __launch_bounds__(256) void post_kernel(
    const unsigned short* __restrict__ pd, const float* __restrict__ ldv,
    const unsigned short* __restrict__ pe, const float* __restrict__ lev,
    const unsigned short* __restrict__ Wl,
    const float* __restrict__ bv_d, const float* __restrict__ ob_d,
    const float* __restrict__ bv_e, const float* __restrict__ ob_e,
    const float* __restrict__ ln2g, const float* __restrict__ ln2b,
    const float* __restrict__ b1, const float* __restrict__ b2,
    float* __restrict__ lat) {
  const unsigned short* wv_d = Wl;
  const unsigned short* ow_d = Wl + 16384;
  const unsigned short* wv_e = Wl + 32768;
  const unsigned short* ow_e = Wl + 49152;
  const unsigned short* w1   = Wl + 65536;
  const unsigned short* w2   = Wl + 98304;

  __shared__ __align__(16) unsigned short sX[64 * 136];
  __shared__ __align__(16) unsigned short sVH[16 * 136];
  __shared__ __align__(16) unsigned short sF[16 * 264];
  __shared__ __align__(16) float sAcc[16 * 132];
  __shared__ float sLd[64], sLe[64];

  const int tid = threadIdx.x;
  const int b = blockIdx.x;
  const int lane = tid & 63;
  const int w = tid >> 6;
  const int m = lane & 15;
  const int quad = lane >> 4;

  if (tid < 64) {
    float v = ldv[(size_t)b * 64 + tid];
    sLd[tid] = (v > 0.f) ? 1.f / v : 0.f;
  } else if (tid < 128) {
    int r = tid - 64;
    float v = lev[((size_t)b * 4 + 0) * 64 + r] + lev[((size_t)b * 4 + 1) * 64 + r]
            + lev[((size_t)b * 4 + 2) * 64 + r] + lev[((size_t)b * 4 + 3) * 64 + r];
    sLe[r] = (v > 0.f) ? 1.f / v : 0.f;
  }
  __syncthreads();
  {
    const ushort4* src = (const ushort4*)(pd + (size_t)b * 8192);
#pragma unroll
    for (int it = 0; it < 8; ++it) {
      int f = tid + it * 256;
      int row = f >> 5, d = (f & 31) * 4;
      ushort4 u = src[f];
      float sc = sLd[row];
      ushort4 o = { f2bf(bf2f(u.x) * sc), f2bf(bf2f(u.y) * sc),
                    f2bf(bf2f(u.z) * sc), f2bf(bf2f(u.w) * sc) };
      *(ushort4*)(sX + row * 136 + d) = o;
    }
  }
  __syncthreads();
  {
    short8 aF[4];
    const unsigned short* arow = sX + (w * 16 + m) * 136 + quad * 8;
#pragma unroll
    for (int c = 0; c < 4; ++c) aF[c] = *(const short8*)(arow + c * 32);
#pragma unroll
    for (int t = 0; t < 2; ++t) {
      int n = w * 32 + t * 16 + m;
      floatx4 acc = (floatx4){0.f, 0.f, 0.f, 0.f};
      const unsigned short* brow = wv_d + n * 128 + quad * 8;
#pragma unroll
      for (int c = 0; c < 4; ++c)
        acc = __builtin_amdgcn_mfma_f32_16x16x32_bf16(aF[c], *(const short8*)(brow + c * 32), acc, 0, 0, 0);
      float bb = bv_d[n];
#pragma unroll
      for (int r = 0; r < 4; ++r) sVH[(quad * 4 + r) * 136 + n] = f2bf(acc[r] + bb);
    }
  }
  __syncthreads();
  {
    short8 aF[4];
    const unsigned short* arow = sVH + m * 136 + quad * 8;
#pragma unroll
    for (int c = 0; c < 4; ++c) aF[c] = *(const short8*)(arow + c * 32);
#pragma unroll
    for (int t = 0; t < 2; ++t) {
      int n = w * 32 + t * 16 + m;
      floatx4 acc = (floatx4){0.f, 0.f, 0.f, 0.f};
      const unsigned short* brow = ow_d + n * 128 + quad * 8;
#pragma unroll
      for (int c = 0; c < 4; ++c)
        acc = __builtin_amdgcn_mfma_f32_16x16x32_bf16(aF[c], *(const short8*)(brow + c * 32), acc, 0, 0, 0);
      float bb = ob_d[n];
#pragma unroll
      for (int r = 0; r < 4; ++r) {
        int q = quad * 4 + r;
        sAcc[q * 132 + n] = lat[(size_t)b * 2048 + q * 128 + n] + acc[r] + bb;
      }
    }
  }
  __syncthreads();
  {
    const ushort4* s0 = (const ushort4*)(pe + ((size_t)b * 4 + 0) * 8192);
    const ushort4* s1 = (const ushort4*)(pe + ((size_t)b * 4 + 1) * 8192);
    const ushort4* s2 = (const ushort4*)(pe + ((size_t)b * 4 + 2) * 8192);
    const ushort4* s3 = (const ushort4*)(pe + ((size_t)b * 4 + 3) * 8192);
#pragma unroll
    for (int it = 0; it < 8; ++it) {
      int f = tid + it * 256;
      int row = f >> 5, d = (f & 31) * 4;
      ushort4 u0 = s0[f], u1 = s1[f], u2 = s2[f], u3 = s3[f];
      float sc = sLe[row];
      ushort4 o = { f2bf((bf2f(u0.x) + bf2f(u1.x) + bf2f(u2.x) + bf2f(u3.x)) * sc),
                    f2bf((bf2f(u0.y) + bf2f(u1.y) + bf2f(u2.y) + bf2f(u3.y)) * sc),
                    f2bf((bf2f(u0.z) + bf2f(u1.z) + bf2f(u2.z) + bf2f(u3.z)) * sc),
                    f2bf((bf2f(u0.w) + bf2f(u1.w) + bf2f(u2.w) + bf2f(u3.w)) * sc) };
      *(ushort4*)(sX + row * 136 + d) = o;
    }
  }
  __syncthreads();
  {
    short8 aF[4];
    const unsigned short* arow = sX + (w * 16 + m) * 136 + quad * 8;
#pragma unroll
    for (int c = 0; c < 4; ++c) aF[c] = *(const short8*)(arow + c * 32);
#pragma unroll
    for (int t = 0; t < 2; ++t) {
      int n = w * 32 + t * 16 + m;
      floatx4 acc = (floatx4){0.f, 0.f, 0.f, 0.f};
      const unsigned short* brow = wv_e + n * 128 + quad * 8;
#pragma unroll
      for (int c = 0; c < 4; ++c)
        acc = __builtin_amdgcn_mfma_f32_16x16x32_bf16(aF[c], *(const short8*)(brow + c * 32), acc, 0, 0, 0);
      float bb = bv_e[n];
#pragma unroll
      for (int r = 0; r < 4; ++r) sVH[(quad * 4 + r) * 136 + n] = f2bf(acc[r] + bb);
    }
  }
  __syncthreads();
  {
    short8 aF[4];
    const unsigned short* arow = sVH + m * 136 + quad * 8;
#pragma unroll
    for (int c = 0; c < 4; ++c) aF[c] = *(const short8*)(arow + c * 32);
#pragma unroll
    for (int t = 0; t < 2; ++t) {
      int n = w * 32 + t * 16 + m;
      floatx4 acc = (floatx4){0.f, 0.f, 0.f, 0.f};
      const unsigned short* brow = ow_e + n * 128 + quad * 8;
#pragma unroll
      for (int c = 0; c < 4; ++c)
        acc = __builtin_amdgcn_mfma_f32_16x16x32_bf16(aF[c], *(const short8*)(brow + c * 32), acc, 0, 0, 0);
      float bb = ob_e[n];
#pragma unroll
      for (int r = 0; r < 4; ++r) {
        int q = quad * 4 + r;
        sAcc[q * 132 + n] += acc[r] + bb;
      }
    }
  }
  __syncthreads();
  {
    int q = tid >> 4, li = tid & 15, d0 = li * 8;
    float x[8];
#pragma unroll
    for (int j = 0; j < 8; ++j) x[j] = sAcc[q * 132 + d0 + j];
    float s1 = 0.f, s2 = 0.f;
#pragma unroll
    for (int j = 0; j < 8; ++j) { s1 += x[j]; s2 += x[j] * x[j]; }
#pragma unroll
    for (int o = 1; o < 16; o <<= 1) { s1 += __shfl_xor(s1, o); s2 += __shfl_xor(s2, o); }
    float mean = s1 * (1.f / 128.f);
    float var = s2 * (1.f / 128.f) - mean * mean;
    float rstd = rsqrtf(var + 1e-5f);
    float y[8];
#pragma unroll
    for (int j = 0; j < 8; ++j)
      y[j] = (x[j] - mean) * rstd * ln2g[d0 + j] + ln2b[d0 + j];
    ushort4 o0 = { f2bf(y[0]), f2bf(y[1]), f2bf(y[2]), f2bf(y[3]) };
    ushort4 o1 = { f2bf(y[4]), f2bf(y[5]), f2bf(y[6]), f2bf(y[7]) };
    *(ushort4*)(sX + q * 136 + d0) = o0;
    *(ushort4*)(sX + q * 136 + d0 + 4) = o1;
  }
  __syncthreads();
  {
    short8 aF[4];
    const unsigned short* arow = sX + m * 136 + quad * 8;
#pragma unroll
    for (int c = 0; c < 4; ++c) aF[c] = *(const short8*)(arow + c * 32);
#pragma unroll
    for (int t = 0; t < 4; ++t) {
      int n = w * 64 + t * 16 + m;
      floatx4 acc = (floatx4){0.f, 0.f, 0.f, 0.f};
      const unsigned short* brow = w1 + n * 128 + quad * 8;
#pragma unroll
      for (int c = 0; c < 4; ++c)
        acc = __builtin_amdgcn_mfma_f32_16x16x32_bf16(aF[c], *(const short8*)(brow + c * 32), acc, 0, 0, 0);
      float bb = b1[n];
#pragma unroll
      for (int r = 0; r < 4; ++r)
        sF[(quad * 4 + r) * 264 + n] = f2bf(fmaxf(acc[r] + bb, 0.f));
    }
  }
  __syncthreads();
  {
    short8 aF[8];
    const unsigned short* arow = sF + m * 264 + quad * 8;
#pragma unroll
    for (int c = 0; c < 8; ++c) aF[c] = *(const short8*)(arow + c * 32);
#pragma unroll
    for (int t = 0; t < 2; ++t) {
      int n = w * 32 + t * 16 + m;
      floatx4 acc = (floatx4){0.f, 0.f, 0.f, 0.f};
      const unsigned short* brow = w2 + n * 256 + quad * 8;
#pragma unroll
      for (int c = 0; c < 8; ++c)
        acc = __builtin_amdgcn_mfma_f32_16x16x32_bf16(aF[c], *(const short8*)(brow + c * 32), acc, 0, 0, 0);
      float bb = b2[n];
#pragma unroll
      for (int r = 0; r < 4; ++r) {
        int q = quad * 4 + r;
        lat[(size_t)b * 2048 + q * 128 + n] = sAcc[q * 132 + n] + acc[r] + bb;
      }
    }
  }
}

// ---------------- head ----------------
__global__ __launch_bounds__(256) void head_kernel(const float* __restrict__ lat,
                                                   const float* __restrict__ w1,
                                                   const float* __restrict__ b1,
                                                   const float* __restrict__ w2,
                                                   const float* __restrict__ b2,
                                                   float* __restrict__ out) {
  __shared__ __align__(16) float sX[2048];
  __shared__ float sH[128];
  const int tid = threadIdx.x;
  const int b = blockIdx.x;
  {
    const float4* src = (const float4*)(lat + (size_t)b * 2048);
#pragma unroll
    for (int it = 0; it < 2; ++it) ((float4*)sX)[tid + it * 256] = src[tid + it * 256];
  }
  __syncthreads();
  {
    int o = tid >> 1, kh = tid & 1;
    float a = 0.f;
    const float* wr = w1 + (size_t)o * 2048 + kh * 1024;
    const float* xb = sX + kh * 1024;
    for (int k4 = 0; k4 < 256; ++k4) {
      float4 w4 = *(const float4*)(wr + k4 * 4);
      float4 x4 = *(const float4*)(xb + k4 * 4);
      a += w4.x * x4.x + w4.y * x4.y + w4.z * x4.z + w4.w * x4.w;
    }
    a += __shfl_xor(a, 1);
    if (kh == 0) sH[o] = fmaxf(a + b1[o], 0.f);
  }
  __syncthreads();
  if (tid < 64) {
    float a = sH[tid] * w2[tid] + sH[tid + 64] * w2[tid + 64];
#pragma unroll
    for (int o = 1; o < 64; o <<= 1) a += __shfl_xor(a, o);
    if (tid == 0) {
      float x = a + b2[0];
      out[b] = (x > 20.f) ? x : log1pf(__expf(x));
    }
  }
}

extern "C" void kernel_launch(void* const* d_in, const int* in_sizes, int n_in,
                              void* d_out, int out_size, void* d_ws, size_t ws_size,
                              hipStream_t stream) {
  const float* drug_k  = (const float*)d_in[0];
  const float* drug_v  = (const float*)d_in[1];
  const float* enz_k   = (const float*)d_in[2];
  const float* enz_v   = (const float*)d_in[3];
  const int*   drug_b  = (const int*)d_in[4];
  const int*   enz_b   = (const int*)d_in[5];
  const float* latents = (const float*)d_in[6];
  const float* wq_d    = (const float*)d_in[7];
  const float* bq_d    = (const float*)d_in[8];
  const float* wq_e    = (const float*)d_in[9];
  const float* bq_e    = (const float*)d_in[10];
  const float* mha_d_w = (const float*)d_in[11];
  const float* mha_d_b = (const float*)d_in[12];
  const float* mha_d_ow= (const float*)d_in[13];
  const float* mha_d_ob= (const float*)d_in[14];
  const float* mha_e_w = (const float*)d_in[15];
  const float* mha_e_b = (const float*)d_in[16];
  const float* mha_e_ow= (const float*)d_in[17];
  const float* mha_e_ob= (const float*)d_in[18];
  const float* ln1_g   = (const float*)d_in[19];
  const float* ln1_b   = (const float*)d_in[20];
  const float* ln2_g   = (const float*)d_in[21];
  const float* ln2_b   = (const float*)d_in[22];
  const float* ffn_w1  = (const float*)d_in[23];
  const float* ffn_b1  = (const float*)d_in[24];
  const float* ffn_w2  = (const float*)d_in[25];
  const float* ffn_b2  = (const float*)d_in[26];
  const float* head_w1 = (const float*)d_in[27];
  const float* head_b1 = (const float*)d_in[28];
  const float* head_w2 = (const float*)d_in[29];
  const float* head_b2 = (const float*)d_in[30];
  float* out = (float*)d_out;

  const int n_dk = in_sizes[0];   // 25600*128
  const int n_ek = in_sizes[2];   // 153600*128

  int* seg = (int*)d_ws;
  float* fws = (float*)d_ws;
  float* Wqf = fws + 2048;
  float* bqf = Wqf + 131072;
  float* lat = bqf + 1024;
  float* l_d = lat + 1048576;
  float* l_e = l_d + 32768;
  unsigned short* Qt     = (unsigned short*)(l_e + 131072);
  unsigned short* part_d = Qt + 8388608;
  unsigned short* part_e = part_d + 4194304;
  unsigned short* Kd_bf  = part_e + 16777216;
  unsigned short* Vd_bf  = Kd_bf + n_dk;
  unsigned short* Ke_bf  = Vd_bf + n_dk;
  unsigned short* Ve_bf  = Ke_bf + n_ek;
  unsigned short* Wbf    = Ve_bf + n_ek;      // 524288 ush
  unsigned short* WtB    = Wbf + 524288;      // 524288 ush
  float* bt              = (float*)(WtB + 524288);  // 4096 floats

  seg_kernel<<<2, 512, 0, stream>>>(drug_b, in_sizes[4], enz_b, in_sizes[5], seg);
  init_lat_kernel<<<1024, 256, 0, stream>>>(latents, lat);
  fold_kernel<<<64, 256, 0, stream>>>(wq_d, bq_d, wq_e, bq_e,
                                      mha_d_w, mha_d_b, mha_e_w, mha_e_b, Wqf, bqf);
  wt_kernel<<<32, 256, 0, stream>>>(Wqf, bqf, mha_d_w, mha_e_w, WtB, bt);
  {
    int na4 = n_dk / 4, nc4 = n_ek / 4;
    int tot = na4 * 2 + nc4 * 2;
    cvt4_kernel<<<(tot + 255) / 256, 256, 0, stream>>>(
        drug_k, Kd_bf, na4, drug_v, Vd_bf, na4, enz_k, Ke_bf, nc4, enz_v, Ve_bf, nc4);
  }
  cvtw_kernel<<<512, 256, 0, stream>>>(mha_d_w, mha_d_ow, mha_e_w, mha_e_ow,
                                       ffn_w1, ffn_w2, Wbf);
  for (int l = 0; l < 4; ++l) {
    qtilde_kernel<<<512, 256, 0, stream>>>(lat, ln1_g + l * 128, ln1_b + l * 128,
        WtB + (size_t)l * 131072, bt + l * 1024, Qt);
    attn3_kernel<<<2560, 256, 0, stream>>>(Kd_bf, Vd_bf, Ke_bf, Ve_bf, seg,
        Qt, part_d, l_d, part_e, l_e);
    post_kernel<<<512, 256, 0, stream>>>(part_d, l_d, part_e, l_e,
        Wbf + (size_t)l * 131072,
        mha_d_b + l * 384 + 256, mha_d_ob + l * 128,
        mha_e_b + l * 384 + 256, mha_e_ob + l * 128,
        ln2_g + l * 128, ln2_b + l * 128,
        ffn_b1 + l * 256, ffn_b2 + l * 128,
        lat);
  }
  head_kernel<<<512, 256, 0, stream>>>(lat, head_w1, head_b1, head_w2, head_b2, out);
}